// Round 14
// baseline (152.375 us; speedup 1.0000x reference)
//
#include <hip/hip_runtime.h>
#include <hip/hip_bf16.h>

// ---------------------------------------------------------------------------
// GNN classifier on MI355X.
//   h0 = relu([shape_emb[x0]|color_emb[x1]] @ W_in + b_in)   -> 64-entry table
//   conv1: h1 = relu( seg_sum(hltab[type[src]],dst)/deg + hrtab[type] )
//   conv2 by linearity:  g1 = h1@W2l, r1 = h1@W2r + b2  (bf16 MFMA GEMM)
//          h2 = relu( seg_sum(g1[src],dst)/deg + r1 )
//   out   = seg_sum(h2@W_out, batch)/cnt + b_out   (fused into the gather)
//
// R2: full-unroll spill lesson. R3: sorted batch -> deferred pooling flush.
// R4: no atomic-with-return on critical path. R5: coalesced edge loads +
// __shfl broadcast. R6: packed-bf16 intermediates halve gather traffic.
// R7: bucketed LDS sort replaces 1.2M device-scope atomics. R8: feature-pair
// lanes double gather2 MLP (44us, ~3.5TB/s logical = concurrency ceiling).
// R9: h1/r1 bf16; fused tab kernels. R10: MFMA lin2; 8 dispatches.
// R11: NBLK 256, gather1 ILP-8.
// R12: 16-edge loop regressed (mean degree 12 -> block never runs; longer
//      serial shfl preamble, occupancy 63->39%). Reverted; keep 8-edge form.
// R13: software-pipeline the per-node independent loads in both gathers:
//      prefetch node j+1's first csrp chunk (and r1p row in gather2) while
//      node j's gather is in flight. Removes ~500cy serial L2 latency per
//      node without touching the proven inner-loop structure.
// ---------------------------------------------------------------------------

#define NBLK 256   // blocks used by hist / scatter (chunked edge partition)

typedef __attribute__((ext_vector_type(8))) short bf16x8;
typedef __attribute__((ext_vector_type(4))) float f32x4;

__device__ __forceinline__ unsigned bf16rn(float x) {
    unsigned b = __float_as_uint(x);
    return (b + 0x7FFFu + ((b >> 16) & 1u)) >> 16;       // round-to-nearest-even
}
__device__ __forceinline__ unsigned bf16pack2(float lo, float hi) {
    return bf16rn(lo) | (bf16rn(hi) << 16);
}

// exclusive scan of btot[0..nb) into bb[0..512) (LDS), done by wave 0.
__device__ __forceinline__ void scan_btot(const int* __restrict__ btot, int nb,
                                          int* __restrict__ bb) {
    int tid = threadIdx.x;
    if (tid < 64) {
        int v[8]; int s = 0;
#pragma unroll
        for (int e = 0; e < 8; ++e) {
            int idx = tid * 8 + e;
            v[e] = s;
            s += (idx < nb) ? btot[idx] : 0;
        }
        int ex = s;
#pragma unroll
        for (int ofs = 1; ofs < 64; ofs <<= 1) {
            int t = __shfl_up(ex, ofs);
            if (tid >= ofs) ex += t;
        }
        ex -= s;                                  // exclusive prefix of lane sums
#pragma unroll
        for (int e = 0; e < 8; ++e) bb[tid * 8 + e] = ex + v[e];
    }
    __syncthreads();
}

// fused front-end: blocks [0,NBLK) histogram; [NBLK,NBLK+64) build tables;
// [NBLK+64, ...) ntype + accumulator zeroing. Disjoint roles, no stragglers.
__global__ __launch_bounds__(256) void k_front(
    const int* __restrict__ dst, int* __restrict__ histT, int n_edges, int nb,
    const float* __restrict__ se, const float* __restrict__ ce,
    const float* __restrict__ Win, const float* __restrict__ bin,
    const float* __restrict__ W1l, const float* __restrict__ W1r,
    const float* __restrict__ b1, float* __restrict__ hltab, float* __restrict__ hrtab,
    const int* __restrict__ x, int* __restrict__ ntype,
    float* __restrict__ cnt, float* __restrict__ outacc, int n_nodes, int n_graphs) {
    int blk = blockIdx.x, tid = threadIdx.x;
    if (blk < NBLK) {                                       // ---- histogram
        __shared__ int h[512];
        for (int i = tid; i < nb; i += 256) h[i] = 0;
        __syncthreads();
        int per = (n_edges + NBLK - 1) / NBLK;
        int e0 = blk * per;
        int e1 = e0 + per; if (e1 > n_edges) e1 = n_edges;
        for (int e = e0 + tid; e < e1; e += 256)
            atomicAdd(&h[dst[e] >> 8], 1);
        __syncthreads();
        for (int i = tid; i < nb; i += 256)
            histT[(size_t)i * NBLK + blk] = h[i];
    } else if (blk < NBLK + 64) {                           // ---- tables
        __shared__ float sse[64], sce[64], sh0[64];
        int t = blk - NBLK, j = tid;
        if (j < 64) {
            int s = t >> 3, c = t & 7;
            sse[j] = se[s * 64 + j];
            sce[j] = ce[c * 64 + j];
        }
        __syncthreads();
        if (j < 64) {
            float acc = bin[j];
            for (int k = 0; k < 64; ++k) {
                acc += sse[k] * Win[k * 64 + j];
                acc += sce[k] * Win[(64 + k) * 64 + j];
            }
            sh0[j] = fmaxf(acc, 0.f);
        }
        __syncthreads();
        if (j < 64) {
            float al = 0.f, ar = b1[j];
            for (int k = 0; k < 64; ++k) {
                float h = sh0[k];
                al += h * W1l[k * 64 + j];
                ar += h * W1r[k * 64 + j];
            }
            hltab[t * 64 + j] = al;
            hrtab[t * 64 + j] = ar;
        }
    } else {                                                // ---- prep + zero
        int n = (blk - NBLK - 64) * 256 + tid;
        if (n < n_nodes) {
            int2 v = *(const int2*)(x + 2 * (size_t)n);
            ntype[n] = v.x * 8 + v.y;
        }
        if (n < n_graphs) cnt[n] = 0.f;
        if (n < 2 * n_graphs) outacc[n] = 0.f;
    }
}

// per-bucket exclusive scan over the NBLK block counts (NBLK == 256).
__global__ __launch_bounds__(256) void k_bscan(const int* __restrict__ histT,
                                               int* __restrict__ blockOff,
                                               int* __restrict__ btot) {
    __shared__ int sbuf[2][256];
    int b = blockIdx.x, tid = threadIdx.x;
    int d = histT[(size_t)b * NBLK + tid];
    int cur = 0;
    sbuf[0][tid] = d;
    __syncthreads();
    for (int ofs = 1; ofs < 256; ofs <<= 1) {
        int v = sbuf[cur][tid];
        if (tid >= ofs) v += sbuf[cur][tid - ofs];
        sbuf[cur ^ 1][tid] = v;
        cur ^= 1;
        __syncthreads();
    }
    blockOff[(size_t)b * NBLK + tid] = sbuf[cur][tid] - d;
    if (tid == 255) btot[b] = sbuf[cur][tid];
}

// scatter edges into bucket-grouped order; bucket bases recomputed locally.
__global__ __launch_bounds__(256) void k_scatter(
    const int* __restrict__ src, const int* __restrict__ dst,
    const int* __restrict__ ntype, const int* __restrict__ btot,
    const int* __restrict__ blockOff, int* __restrict__ bedge,
    int n_edges, int nb) {
    __shared__ int bb[512];
    __shared__ int cur[512];
    int tid = threadIdx.x, blk = blockIdx.x;
    scan_btot(btot, nb, bb);
    for (int i = tid; i < nb; i += 256)
        cur[i] = bb[i] + blockOff[(size_t)i * NBLK + blk];
    __syncthreads();
    int per = (n_edges + NBLK - 1) / NBLK;
    int e0 = blk * per;
    int e1 = e0 + per; if (e1 > n_edges) e1 = n_edges;
    for (int e = e0 + tid; e < e1; e += 256) {
        int d = dst[e], s = src[e];
        int pos = atomicAdd(&cur[d >> 8], 1);       // LDS atomic (fast)
        bedge[pos] = s | (ntype[s] << 17) | ((d & 255) << 23);
    }
}

// per-bucket 256-way counting sort in LDS; emits deg/off/inv + final csrp.
__global__ __launch_bounds__(256) void k_bsort(
    const int* __restrict__ bedge, const int* __restrict__ btot,
    int* __restrict__ csrp, int* __restrict__ deg, int* __restrict__ off,
    float* __restrict__ inv, int n_nodes, int nb) {
    __shared__ int bb[512];
    __shared__ int cnt[256];
    __shared__ int sbuf[2][256];
    __shared__ int loff[256];
    int b = blockIdx.x, tid = threadIdx.x;
    scan_btot(btot, nb, bb);
    int base = bb[b], tot = btot[b];
    cnt[tid] = 0;
    __syncthreads();
    for (int i = tid; i < tot; i += 256)
        atomicAdd(&cnt[(bedge[base + i] >> 23) & 255], 1);
    __syncthreads();
    int d = cnt[tid];
    int cur = 0;
    sbuf[0][tid] = d;
    __syncthreads();
    for (int ofs = 1; ofs < 256; ofs <<= 1) {
        int v = sbuf[cur][tid];
        if (tid >= ofs) v += sbuf[cur][tid - ofs];
        sbuf[cur ^ 1][tid] = v;
        cur ^= 1;
        __syncthreads();
    }
    loff[tid] = sbuf[cur][tid] - d;                  // exclusive within bucket
    __syncthreads();
    int n = b * 256 + tid;
    if (n < n_nodes) {
        deg[n] = d;
        off[n] = base + loff[tid];
        inv[n] = 1.0f / fmaxf((float)d, 1.0f);
    }
    cnt[tid] = loff[tid];                            // reuse as cursor
    __syncthreads();
    for (int i = tid; i < tot; i += 256) {
        int v = bedge[base + i];
        int pos = atomicAdd(&cnt[(v >> 23) & 255], 1);
        csrp[base + pos] = (v & 0x1FFFF) | (((v >> 17) & 63) << 20);
    }
}

// ---- compute kernels --------------------------------------------------------

// conv1; h1 written as PACKED BF16 rows. ILP-8 LDS chain + next-node csrp
// chunk prefetch (R13).
__global__ __launch_bounds__(256) void k_gather1(
    const int* __restrict__ csrp, const int* __restrict__ off,
    const int* __restrict__ deg_i, const float* __restrict__ inv,
    const int* __restrict__ ntype, const float* __restrict__ hltab,
    const float* __restrict__ hrtab, unsigned* __restrict__ h1p, int n_nodes) {
    __shared__ float tl[4096];
    __shared__ float tr_[4096];
    for (int i = threadIdx.x; i < 4096; i += 256) { tl[i] = hltab[i]; tr_[i] = hrtab[i]; }
    __syncthreads();
    int lane = threadIdx.x & 63;
    int w = blockIdx.x * 4 + (threadIdx.x >> 6);
    int nw = gridDim.x * 4;
    int per = (n_nodes + nw - 1) / nw;
    int n0 = w * per;
    int n1 = n0 + per; if (n1 > n_nodes) n1 = n_nodes;
    for (int cb = n0; cb < n1; cb += 64) {
        int cn = n1 - cb; if (cn > 64) cn = 64;
        int voff = 0, vdeg = 0, vnt = 0; float vinv = 0.f;
        if (lane < cn) {
            voff = off[cb + lane]; vdeg = deg_i[cb + lane];
            vinv = inv[cb + lane]; vnt  = ntype[cb + lane];
        }
        // prefetch node 0's first csrp chunk
        int o_nx = __shfl(voff, 0), d_nx = __shfl(vdeg, 0);
        int v_nx = (lane < (d_nx < 64 ? d_nx : 64)) ? csrp[o_nx + lane] : 0;
        for (int j = 0; j < cn; ++j) {
            int o = o_nx, d = d_nx, vfirst = v_nx;
            float iv = __shfl(vinv, j);
            int tn = __shfl(vnt, j);
            if (j + 1 < cn) {                    // prefetch next node (R13)
                o_nx = __shfl(voff, j + 1);
                d_nx = __shfl(vdeg, j + 1);
                v_nx = (lane < (d_nx < 64 ? d_nx : 64)) ? csrp[o_nx + lane] : 0;
            }
            float acc = 0.f;
            for (int base = 0; base < d; base += 64) {
                int rem = d - base; if (rem > 64) rem = 64;
                int v = (base == 0) ? vfirst : ((lane < rem) ? csrp[o + base + lane] : 0);
                int k = 0;
                int full8 = rem & ~7;
                for (; k < full8; k += 8) {
                    float s0 = tl[(__shfl(v, k)     >> 20) * 64 + lane];
                    float s1 = tl[(__shfl(v, k + 1) >> 20) * 64 + lane];
                    float s2 = tl[(__shfl(v, k + 2) >> 20) * 64 + lane];
                    float s3 = tl[(__shfl(v, k + 3) >> 20) * 64 + lane];
                    float s4 = tl[(__shfl(v, k + 4) >> 20) * 64 + lane];
                    float s5 = tl[(__shfl(v, k + 5) >> 20) * 64 + lane];
                    float s6 = tl[(__shfl(v, k + 6) >> 20) * 64 + lane];
                    float s7 = tl[(__shfl(v, k + 7) >> 20) * 64 + lane];
                    acc += ((s0 + s1) + (s2 + s3)) + ((s4 + s5) + (s6 + s7));
                }
                for (; k < rem; ++k)
                    acc += tl[(__shfl(v, k) >> 20) * 64 + lane];
            }
            float val = fmaxf(acc * iv + tr_[tn * 64 + lane], 0.f);
            float vhi = __shfl_down(val, 1);
            if (!(lane & 1))
                h1p[(size_t)(cb + j) * 32 + (lane >> 1)] = bf16pack2(val, vhi);
        }
    }
}

// conv2 dense GEMMs on MFMA bf16 (R10): g1 = h1@W2l, r1 = h1@W2r + b2.
__global__ __launch_bounds__(256) void k_lin2(
    const unsigned* __restrict__ h1p, const float* __restrict__ W2l,
    const float* __restrict__ W2r, const float* __restrict__ b2,
    unsigned* __restrict__ g1p, unsigned* __restrict__ r1p, int n_nodes) {
    __shared__ uint4 sB[2][4][2][64];    // [mat][nblk][kstep][lane]
    __shared__ float sb2[64];
    int tid = threadIdx.x;
    for (int i = tid; i < 1024; i += 256) {
        int mat = i >> 9, nb = (i >> 7) & 3, ks = (i >> 6) & 1, ln = i & 63;
        const float* W = mat ? W2r : W2l;
        int col = nb * 16 + (ln & 15);
        int kbase = ks * 32 + (ln >> 4) * 8;
        unsigned p0 = bf16pack2(W[(kbase + 0) * 64 + col], W[(kbase + 1) * 64 + col]);
        unsigned p1 = bf16pack2(W[(kbase + 2) * 64 + col], W[(kbase + 3) * 64 + col]);
        unsigned p2 = bf16pack2(W[(kbase + 4) * 64 + col], W[(kbase + 5) * 64 + col]);
        unsigned p3 = bf16pack2(W[(kbase + 6) * 64 + col], W[(kbase + 7) * 64 + col]);
        sB[mat][nb][ks][ln] = make_uint4(p0, p1, p2, p3);
    }
    if (tid < 64) sb2[tid] = b2[tid];
    __syncthreads();

    int w = tid >> 6, lane = tid & 63;
    int kg = lane >> 4;
    unsigned short* gh = (unsigned short*)g1p;
    unsigned short* rh = (unsigned short*)r1p;
    int ntile = (n_nodes + 63) >> 6;

    for (int t = blockIdx.x; t < ntile; t += gridDim.x) {
        int n0 = t << 6;
        int row = n0 + w * 16 + (lane & 15);
        int rowc = row < n_nodes ? row : n_nodes - 1;
        uint4 a0u = *(const uint4*)(h1p + (size_t)rowc * 32 + kg * 4);
        uint4 a1u = *(const uint4*)(h1p + (size_t)rowc * 32 + 16 + kg * 4);
        bf16x8 A0 = __builtin_bit_cast(bf16x8, a0u);
        bf16x8 A1 = __builtin_bit_cast(bf16x8, a1u);

        f32x4 accg[4], accr[4];
#pragma unroll
        for (int nb = 0; nb < 4; ++nb) {
            f32x4 z = {0.f, 0.f, 0.f, 0.f};
            bf16x8 Bg0 = __builtin_bit_cast(bf16x8, sB[0][nb][0][lane]);
            bf16x8 Bg1 = __builtin_bit_cast(bf16x8, sB[0][nb][1][lane]);
            bf16x8 Br0 = __builtin_bit_cast(bf16x8, sB[1][nb][0][lane]);
            bf16x8 Br1 = __builtin_bit_cast(bf16x8, sB[1][nb][1][lane]);
            accg[nb] = __builtin_amdgcn_mfma_f32_16x16x32_bf16(A0, Bg0, z, 0, 0, 0);
            accg[nb] = __builtin_amdgcn_mfma_f32_16x16x32_bf16(A1, Bg1, accg[nb], 0, 0, 0);
            accr[nb] = __builtin_amdgcn_mfma_f32_16x16x32_bf16(A0, Br0, z, 0, 0, 0);
            accr[nb] = __builtin_amdgcn_mfma_f32_16x16x32_bf16(A1, Br1, accr[nb], 0, 0, 0);
        }
        // C/D layout (verified, guide §3): col = lane&15, row = (lane>>4)*4 + reg
#pragma unroll
        for (int nb = 0; nb < 4; ++nb) {
            int col = nb * 16 + (lane & 15);
            float bias = sb2[col];
#pragma unroll
            for (int reg = 0; reg < 4; ++reg) {
                int r2 = n0 + w * 16 + kg * 4 + reg;
                if (r2 < n_nodes) {
                    gh[(size_t)r2 * 64 + col] = (unsigned short)bf16rn(accg[nb][reg]);
                    rh[(size_t)r2 * 64 + col] = (unsigned short)bf16rn(accr[nb][reg] + bias);
                }
            }
        }
    }
}

// conv2 aggregation + relu + W_out + pooling. R8 feature-pair scheme;
// next-node csrp chunk + r1p row prefetch (R13).
__global__ __launch_bounds__(256) void k_gather2(
    const int* __restrict__ csrp, const int* __restrict__ off,
    const int* __restrict__ deg_i, const float* __restrict__ inv,
    const unsigned* __restrict__ g1p, const unsigned* __restrict__ r1p,
    const int* __restrict__ batch, const float* __restrict__ Wout,
    float* __restrict__ outacc, float* __restrict__ cnt, int n_nodes) {
    int lane = threadIdx.x & 63;
    int li = lane & 31;                       // feature-pair index (uint in row)
    int hi = lane >> 5;                       // 0: even edges, 1: odd edges
    float hm = hi ? 0.f : 1.f;                // mask so halves don't double-count
    int w = blockIdx.x * 4 + (threadIdx.x >> 6);
    int nw = gridDim.x * 4;
    int per = (n_nodes + nw - 1) / nw;
    int n0 = w * per;
    int n1 = n0 + per; if (n1 > n_nodes) n1 = n_nodes;
    float4 wo = *(const float4*)(Wout + li * 4);   // W[2li][0..1], W[2li+1][0..1]
    float p0 = 0.f, p1 = 0.f, pc = 0.f;
    int curg = -1;
    for (int cb = n0; cb < n1; cb += 64) {
        int cn = n1 - cb; if (cn > 64) cn = 64;
        int voff = 0, vdeg = 0, vbat = 0; float vinv = 0.f;
        if (lane < cn) {
            voff = off[cb + lane]; vdeg = deg_i[cb + lane];
            vinv = inv[cb + lane]; vbat = batch[cb + lane];
        }
        // prefetch node 0's first csrp chunk + r1p row (R13)
        int o_nx = __shfl(voff, 0), d_nx = __shfl(vdeg, 0);
        int v_nx = (lane < (d_nx < 64 ? d_nx : 64)) ? csrp[o_nx + lane] : 0;
        unsigned ur_nx = r1p[(size_t)cb * 32 + li];
        for (int j = 0; j < cn; ++j) {
            int o = o_nx, d = d_nx, vfirst = v_nx;
            unsigned ur = ur_nx;
            int g = __shfl(vbat, j);
            float iv = __shfl(vinv, j);
            if (j + 1 < cn) {                    // prefetch next node (R13)
                o_nx = __shfl(voff, j + 1);
                d_nx = __shfl(vdeg, j + 1);
                v_nx = (lane < (d_nx < 64 ? d_nx : 64)) ? csrp[o_nx + lane] : 0;
                ur_nx = r1p[(size_t)(cb + j + 1) * 32 + li];
            }
            float accL = 0.f, accH = 0.f;     // features 2li, 2li+1
            for (int base = 0; base < d; base += 64) {
                int rem = d - base; if (rem > 64) rem = 64;
                int v = (base == 0) ? vfirst : ((lane < rem) ? csrp[o + base + lane] : 0);
                int k = 0;
                int full8 = rem & ~7;
                for (; k < full8; k += 8) {   // 4 pairs = 8 edges, 4 loads in flight
                    int a0 = __shfl(v, k),     a1 = __shfl(v, k + 1);
                    int a2 = __shfl(v, k + 2), a3 = __shfl(v, k + 3);
                    int a4 = __shfl(v, k + 4), a5 = __shfl(v, k + 5);
                    int a6 = __shfl(v, k + 6), a7 = __shfl(v, k + 7);
                    size_t s0 = (size_t)((hi ? a1 : a0) & 0xFFFFF);
                    size_t s1 = (size_t)((hi ? a3 : a2) & 0xFFFFF);
                    size_t s2 = (size_t)((hi ? a5 : a4) & 0xFFFFF);
                    size_t s3 = (size_t)((hi ? a7 : a6) & 0xFFFFF);
                    unsigned u0 = g1p[s0 * 32 + li];
                    unsigned u1 = g1p[s1 * 32 + li];
                    unsigned u2 = g1p[s2 * 32 + li];
                    unsigned u3 = g1p[s3 * 32 + li];
                    accL += (__uint_as_float(u0 << 16) + __uint_as_float(u1 << 16)) +
                            (__uint_as_float(u2 << 16) + __uint_as_float(u3 << 16));
                    accH += (__uint_as_float(u0 & 0xFFFF0000u) + __uint_as_float(u1 & 0xFFFF0000u)) +
                            (__uint_as_float(u2 & 0xFFFF0000u) + __uint_as_float(u3 & 0xFFFF0000u));
                }
                for (; k + 1 < rem; k += 2) { // single pair
                    int a0 = __shfl(v, k), a1 = __shfl(v, k + 1);
                    size_t s = (size_t)((hi ? a1 : a0) & 0xFFFFF);
                    unsigned u = g1p[s * 32 + li];
                    accL += __uint_as_float(u << 16);
                    accH += __uint_as_float(u & 0xFFFF0000u);
                }
                if (k < rem) {                // odd tail: only hi==0 half counts
                    size_t s = (size_t)(__shfl(v, k) & 0xFFFFF);
                    unsigned u = g1p[s * 32 + li];
                    accL += hm * __uint_as_float(u << 16);
                    accH += hm * __uint_as_float(u & 0xFFFF0000u);
                }
            }
            accL += __shfl_xor(accL, 32);     // merge even/odd halves
            accH += __shfl_xor(accH, 32);
            float v0 = fmaxf(accL * iv + __uint_as_float(ur << 16), 0.f);
            float v1 = fmaxf(accH * iv + __uint_as_float(ur & 0xFFFF0000u), 0.f);
            if (g != curg) {                  // wave-uniform branch
                float q0 = p0, q1 = p1;
#pragma unroll
                for (int m = 1; m < 64; m <<= 1) { q0 += __shfl_xor(q0, m); q1 += __shfl_xor(q1, m); }
                if (lane == 0 && curg >= 0) {
                    atomicAdd(&outacc[curg * 2 + 0], q0);
                    atomicAdd(&outacc[curg * 2 + 1], q1);
                    atomicAdd(&cnt[curg], pc);
                }
                p0 = 0.f; p1 = 0.f; pc = 0.f; curg = g;
            }
            p0 += hm * (v0 * wo.x + v1 * wo.z);
            p1 += hm * (v0 * wo.y + v1 * wo.w);
            pc += 1.0f;
        }
    }
    {
        float q0 = p0, q1 = p1;
#pragma unroll
        for (int m = 1; m < 64; m <<= 1) { q0 += __shfl_xor(q0, m); q1 += __shfl_xor(q1, m); }
        if (lane == 0 && curg >= 0) {
            atomicAdd(&outacc[curg * 2 + 0], q0);
            atomicAdd(&outacc[curg * 2 + 1], q1);
            atomicAdd(&cnt[curg], pc);
        }
    }
}

__global__ void k_out(const float* __restrict__ outacc, const float* __restrict__ cnt,
                      const float* __restrict__ bout, float* __restrict__ out, int n_graphs) {
    int i = blockIdx.x * 256 + threadIdx.x;
    if (i < n_graphs * 2) {
        int g = i >> 1, c = i & 1;
        out[i] = outacc[i] / fmaxf(cnt[g], 1.0f) + bout[c];
    }
}

extern "C" void kernel_launch(void* const* d_in, const int* in_sizes, int n_in,
                              void* d_out, int out_size, void* d_ws, size_t ws_size,
                              hipStream_t stream) {
    const int* x     = (const int*)d_in[0];
    const int* ei    = (const int*)d_in[1];
    const int* batch = (const int*)d_in[2];
    const float* se   = (const float*)d_in[4];
    const float* ce   = (const float*)d_in[5];
    const float* Win  = (const float*)d_in[6];
    const float* bin  = (const float*)d_in[7];
    const float* W1l  = (const float*)d_in[8];
    const float* b1   = (const float*)d_in[9];
    const float* W1r  = (const float*)d_in[10];
    const float* W2l  = (const float*)d_in[11];
    const float* b2   = (const float*)d_in[12];
    const float* W2r  = (const float*)d_in[13];
    const float* Wout = (const float*)d_in[14];
    const float* bout = (const float*)d_in[15];
    float* out = (float*)d_out;

    int n_nodes  = in_sizes[0] / 2;
    int n_edges  = in_sizes[1] / 2;
    int n_graphs = out_size / 2;
    const int* src = ei;
    const int* dst = ei + n_edges;
    int nb = (n_nodes + 255) >> 8;               // buckets (<= 512 for n<131072)

    char* p = (char*)d_ws;
    auto take = [&](size_t bytes) { char* r = p; p += (bytes + 255) & ~(size_t)255; return r; };
    unsigned* h1p    = (unsigned*)take((size_t)n_nodes * 32 * 4);
    unsigned* g1p    = (unsigned*)take((size_t)n_nodes * 32 * 4);
    unsigned* r1p    = (unsigned*)take((size_t)n_nodes * 32 * 4);
    int*      csrp   = (int*)take((size_t)n_edges * 4);
    int*      bedge  = (int*)take((size_t)n_edges * 4);
    int*      ntype  = (int*)take((size_t)n_nodes * 4);
    int*      deg_i  = (int*)take((size_t)n_nodes * 4);
    int*      off    = (int*)take((size_t)n_nodes * 4);
    float*    inv    = (float*)take((size_t)n_nodes * 4);
    int*      histT  = (int*)take((size_t)512 * NBLK * 4);
    int*      blkOff = (int*)take((size_t)512 * NBLK * 4);
    int*      btot   = (int*)take(512 * 4);
    float*    cnt    = (float*)take((size_t)n_graphs * 4);
    float*    outacc = (float*)take((size_t)n_graphs * 8);
    float*    hltab  = (float*)take(4096 * 4);
    float*    hrtab  = (float*)take(4096 * 4);

    int nbN = (n_nodes + 255) / 256;

    k_front<<<NBLK + 64 + nbN, 256, 0, stream>>>(dst, histT, n_edges, nb,
                                                 se, ce, Win, bin, W1l, W1r, b1,
                                                 hltab, hrtab, x, ntype, cnt, outacc,
                                                 n_nodes, n_graphs);
    k_bscan<<<nb, 256, 0, stream>>>(histT, blkOff, btot);
    k_scatter<<<NBLK, 256, 0, stream>>>(src, dst, ntype, btot, blkOff, bedge, n_edges, nb);
    k_bsort<<<nb, 256, 0, stream>>>(bedge, btot, csrp, deg_i, off, inv, n_nodes, nb);
    k_gather1<<<2048, 256, 0, stream>>>(csrp, off, deg_i, inv, ntype, hltab, hrtab, h1p, n_nodes);
    k_lin2<<<1024, 256, 0, stream>>>(h1p, W2l, W2r, b2, g1p, r1p, n_nodes);
    k_gather2<<<2048, 256, 0, stream>>>(csrp, off, deg_i, inv, g1p, r1p, batch, Wout,
                                        outacc, cnt, n_nodes);
    k_out<<<(n_graphs * 2 + 255) / 256, 256, 0, stream>>>(outacc, cnt, bout, out, n_graphs);
}

// Round 15
// 133.240 us; speedup vs baseline: 1.1436x; 1.1436x over previous
//
#include <hip/hip_runtime.h>
#include <hip/hip_bf16.h>

// ---------------------------------------------------------------------------
// GNN classifier on MI355X.
//   h0 = relu([shape_emb[x0]|color_emb[x1]] @ W_in + b_in)   -> 64-entry table
//   conv1: h1 = relu( seg_sum(hltab[type[src]],dst)/deg + hrtab[type] )
//   conv2 by linearity:  g1 = h1@W2l, r1 = h1@W2r + b2  (bf16 MFMA GEMM)
//          h2 = relu( seg_sum(g1[src],dst)/deg + r1 )
//   out   = seg_sum(h2@W_out, batch)/cnt + b_out   (fused into the gather)
//
// R2: full-unroll spill lesson. R3: sorted batch -> deferred pooling flush.
// R4: no atomic-with-return on critical path. R5: coalesced edge loads +
// __shfl broadcast. R6: packed-bf16 intermediates halve gather traffic.
// R7: bucketed LDS sort replaces 1.2M device-scope atomics. R8: feature-pair
// lanes double gather2 MLP (42-44us @ occ 63%, VGPR 28).
// R9: h1/r1 bf16; fused tab kernels. R10: MFMA lin2; 8 dispatches.
// R11: NBLK 256, gather1 ILP-8.
// R12 LESSON: 16-edge loop regressed (mean degree 12 -> block never runs;
//      longer serial shfl preamble, occ 63->39%).
// R14 LESSON: cross-node prefetch ALSO regressed (VGPR 28->36, occ 63->39%,
//      42->58us): for this latency-bound gather, any per-wave ILP gain that
//      raises live ranges loses MORE in wave residency. The R8 8-edge form
//      with VGPR<=28 IS gather2's structural floor (~42us; 20 waves/CU x
//      4x64B in flight / ~700ns = 1.8TB/s = measured). Reverted exactly.
// ---------------------------------------------------------------------------

#define NBLK 256   // blocks used by hist / scatter (chunked edge partition)

typedef __attribute__((ext_vector_type(8))) short bf16x8;
typedef __attribute__((ext_vector_type(4))) float f32x4;

__device__ __forceinline__ unsigned bf16rn(float x) {
    unsigned b = __float_as_uint(x);
    return (b + 0x7FFFu + ((b >> 16) & 1u)) >> 16;       // round-to-nearest-even
}
__device__ __forceinline__ unsigned bf16pack2(float lo, float hi) {
    return bf16rn(lo) | (bf16rn(hi) << 16);
}

// exclusive scan of btot[0..nb) into bb[0..512) (LDS), done by wave 0.
__device__ __forceinline__ void scan_btot(const int* __restrict__ btot, int nb,
                                          int* __restrict__ bb) {
    int tid = threadIdx.x;
    if (tid < 64) {
        int v[8]; int s = 0;
#pragma unroll
        for (int e = 0; e < 8; ++e) {
            int idx = tid * 8 + e;
            v[e] = s;
            s += (idx < nb) ? btot[idx] : 0;
        }
        int ex = s;
#pragma unroll
        for (int ofs = 1; ofs < 64; ofs <<= 1) {
            int t = __shfl_up(ex, ofs);
            if (tid >= ofs) ex += t;
        }
        ex -= s;                                  // exclusive prefix of lane sums
#pragma unroll
        for (int e = 0; e < 8; ++e) bb[tid * 8 + e] = ex + v[e];
    }
    __syncthreads();
}

// fused front-end: blocks [0,NBLK) histogram; [NBLK,NBLK+64) build tables;
// [NBLK+64, ...) ntype + accumulator zeroing. Disjoint roles, no stragglers.
__global__ __launch_bounds__(256) void k_front(
    const int* __restrict__ dst, int* __restrict__ histT, int n_edges, int nb,
    const float* __restrict__ se, const float* __restrict__ ce,
    const float* __restrict__ Win, const float* __restrict__ bin,
    const float* __restrict__ W1l, const float* __restrict__ W1r,
    const float* __restrict__ b1, float* __restrict__ hltab, float* __restrict__ hrtab,
    const int* __restrict__ x, int* __restrict__ ntype,
    float* __restrict__ cnt, float* __restrict__ outacc, int n_nodes, int n_graphs) {
    int blk = blockIdx.x, tid = threadIdx.x;
    if (blk < NBLK) {                                       // ---- histogram
        __shared__ int h[512];
        for (int i = tid; i < nb; i += 256) h[i] = 0;
        __syncthreads();
        int per = (n_edges + NBLK - 1) / NBLK;
        int e0 = blk * per;
        int e1 = e0 + per; if (e1 > n_edges) e1 = n_edges;
        for (int e = e0 + tid; e < e1; e += 256)
            atomicAdd(&h[dst[e] >> 8], 1);
        __syncthreads();
        for (int i = tid; i < nb; i += 256)
            histT[(size_t)i * NBLK + blk] = h[i];
    } else if (blk < NBLK + 64) {                           // ---- tables
        __shared__ float sse[64], sce[64], sh0[64];
        int t = blk - NBLK, j = tid;
        if (j < 64) {
            int s = t >> 3, c = t & 7;
            sse[j] = se[s * 64 + j];
            sce[j] = ce[c * 64 + j];
        }
        __syncthreads();
        if (j < 64) {
            float acc = bin[j];
            for (int k = 0; k < 64; ++k) {
                acc += sse[k] * Win[k * 64 + j];
                acc += sce[k] * Win[(64 + k) * 64 + j];
            }
            sh0[j] = fmaxf(acc, 0.f);
        }
        __syncthreads();
        if (j < 64) {
            float al = 0.f, ar = b1[j];
            for (int k = 0; k < 64; ++k) {
                float h = sh0[k];
                al += h * W1l[k * 64 + j];
                ar += h * W1r[k * 64 + j];
            }
            hltab[t * 64 + j] = al;
            hrtab[t * 64 + j] = ar;
        }
    } else {                                                // ---- prep + zero
        int n = (blk - NBLK - 64) * 256 + tid;
        if (n < n_nodes) {
            int2 v = *(const int2*)(x + 2 * (size_t)n);
            ntype[n] = v.x * 8 + v.y;
        }
        if (n < n_graphs) cnt[n] = 0.f;
        if (n < 2 * n_graphs) outacc[n] = 0.f;
    }
}

// per-bucket exclusive scan over the NBLK block counts (NBLK == 256).
__global__ __launch_bounds__(256) void k_bscan(const int* __restrict__ histT,
                                               int* __restrict__ blockOff,
                                               int* __restrict__ btot) {
    __shared__ int sbuf[2][256];
    int b = blockIdx.x, tid = threadIdx.x;
    int d = histT[(size_t)b * NBLK + tid];
    int cur = 0;
    sbuf[0][tid] = d;
    __syncthreads();
    for (int ofs = 1; ofs < 256; ofs <<= 1) {
        int v = sbuf[cur][tid];
        if (tid >= ofs) v += sbuf[cur][tid - ofs];
        sbuf[cur ^ 1][tid] = v;
        cur ^= 1;
        __syncthreads();
    }
    blockOff[(size_t)b * NBLK + tid] = sbuf[cur][tid] - d;
    if (tid == 255) btot[b] = sbuf[cur][tid];
}

// scatter edges into bucket-grouped order; bucket bases recomputed locally.
__global__ __launch_bounds__(256) void k_scatter(
    const int* __restrict__ src, const int* __restrict__ dst,
    const int* __restrict__ ntype, const int* __restrict__ btot,
    const int* __restrict__ blockOff, int* __restrict__ bedge,
    int n_edges, int nb) {
    __shared__ int bb[512];
    __shared__ int cur[512];
    int tid = threadIdx.x, blk = blockIdx.x;
    scan_btot(btot, nb, bb);
    for (int i = tid; i < nb; i += 256)
        cur[i] = bb[i] + blockOff[(size_t)i * NBLK + blk];
    __syncthreads();
    int per = (n_edges + NBLK - 1) / NBLK;
    int e0 = blk * per;
    int e1 = e0 + per; if (e1 > n_edges) e1 = n_edges;
    for (int e = e0 + tid; e < e1; e += 256) {
        int d = dst[e], s = src[e];
        int pos = atomicAdd(&cur[d >> 8], 1);       // LDS atomic (fast)
        bedge[pos] = s | (ntype[s] << 17) | ((d & 255) << 23);
    }
}

// per-bucket 256-way counting sort in LDS; emits deg/off/inv + final csrp.
__global__ __launch_bounds__(256) void k_bsort(
    const int* __restrict__ bedge, const int* __restrict__ btot,
    int* __restrict__ csrp, int* __restrict__ deg, int* __restrict__ off,
    float* __restrict__ inv, int n_nodes, int nb) {
    __shared__ int bb[512];
    __shared__ int cnt[256];
    __shared__ int sbuf[2][256];
    __shared__ int loff[256];
    int b = blockIdx.x, tid = threadIdx.x;
    scan_btot(btot, nb, bb);
    int base = bb[b], tot = btot[b];
    cnt[tid] = 0;
    __syncthreads();
    for (int i = tid; i < tot; i += 256)
        atomicAdd(&cnt[(bedge[base + i] >> 23) & 255], 1);
    __syncthreads();
    int d = cnt[tid];
    int cur = 0;
    sbuf[0][tid] = d;
    __syncthreads();
    for (int ofs = 1; ofs < 256; ofs <<= 1) {
        int v = sbuf[cur][tid];
        if (tid >= ofs) v += sbuf[cur][tid - ofs];
        sbuf[cur ^ 1][tid] = v;
        cur ^= 1;
        __syncthreads();
    }
    loff[tid] = sbuf[cur][tid] - d;                  // exclusive within bucket
    __syncthreads();
    int n = b * 256 + tid;
    if (n < n_nodes) {
        deg[n] = d;
        off[n] = base + loff[tid];
        inv[n] = 1.0f / fmaxf((float)d, 1.0f);
    }
    cnt[tid] = loff[tid];                            // reuse as cursor
    __syncthreads();
    for (int i = tid; i < tot; i += 256) {
        int v = bedge[base + i];
        int pos = atomicAdd(&cnt[(v >> 23) & 255], 1);
        csrp[base + pos] = (v & 0x1FFFF) | (((v >> 17) & 63) << 20);
    }
}

// ---- compute kernels --------------------------------------------------------

// conv1; h1 written as PACKED BF16 rows. ILP-8 on the LDS-read chain.
__global__ __launch_bounds__(256) void k_gather1(
    const int* __restrict__ csrp, const int* __restrict__ off,
    const int* __restrict__ deg_i, const float* __restrict__ inv,
    const int* __restrict__ ntype, const float* __restrict__ hltab,
    const float* __restrict__ hrtab, unsigned* __restrict__ h1p, int n_nodes) {
    __shared__ float tl[4096];
    __shared__ float tr_[4096];
    for (int i = threadIdx.x; i < 4096; i += 256) { tl[i] = hltab[i]; tr_[i] = hrtab[i]; }
    __syncthreads();
    int lane = threadIdx.x & 63;
    int w = blockIdx.x * 4 + (threadIdx.x >> 6);
    int nw = gridDim.x * 4;
    int per = (n_nodes + nw - 1) / nw;
    int n0 = w * per;
    int n1 = n0 + per; if (n1 > n_nodes) n1 = n_nodes;
    for (int cb = n0; cb < n1; cb += 64) {
        int cn = n1 - cb; if (cn > 64) cn = 64;
        int voff = 0, vdeg = 0, vnt = 0; float vinv = 0.f;
        if (lane < cn) {
            voff = off[cb + lane]; vdeg = deg_i[cb + lane];
            vinv = inv[cb + lane]; vnt  = ntype[cb + lane];
        }
        for (int j = 0; j < cn; ++j) {
            int o = __shfl(voff, j), d = __shfl(vdeg, j);
            float iv = __shfl(vinv, j);
            int tn = __shfl(vnt, j);
            float acc = 0.f;
            for (int base = 0; base < d; base += 64) {
                int rem = d - base; if (rem > 64) rem = 64;
                int v = (lane < rem) ? csrp[o + base + lane] : 0;
                int k = 0;
                int full8 = rem & ~7;
                for (; k < full8; k += 8) {
                    float s0 = tl[(__shfl(v, k)     >> 20) * 64 + lane];
                    float s1 = tl[(__shfl(v, k + 1) >> 20) * 64 + lane];
                    float s2 = tl[(__shfl(v, k + 2) >> 20) * 64 + lane];
                    float s3 = tl[(__shfl(v, k + 3) >> 20) * 64 + lane];
                    float s4 = tl[(__shfl(v, k + 4) >> 20) * 64 + lane];
                    float s5 = tl[(__shfl(v, k + 5) >> 20) * 64 + lane];
                    float s6 = tl[(__shfl(v, k + 6) >> 20) * 64 + lane];
                    float s7 = tl[(__shfl(v, k + 7) >> 20) * 64 + lane];
                    acc += ((s0 + s1) + (s2 + s3)) + ((s4 + s5) + (s6 + s7));
                }
                for (; k < rem; ++k)
                    acc += tl[(__shfl(v, k) >> 20) * 64 + lane];
            }
            float val = fmaxf(acc * iv + tr_[tn * 64 + lane], 0.f);
            float vhi = __shfl_down(val, 1);
            if (!(lane & 1))
                h1p[(size_t)(cb + j) * 32 + (lane >> 1)] = bf16pack2(val, vhi);
        }
    }
}

// conv2 dense GEMMs on MFMA bf16 (R10): g1 = h1@W2l, r1 = h1@W2r + b2.
__global__ __launch_bounds__(256) void k_lin2(
    const unsigned* __restrict__ h1p, const float* __restrict__ W2l,
    const float* __restrict__ W2r, const float* __restrict__ b2,
    unsigned* __restrict__ g1p, unsigned* __restrict__ r1p, int n_nodes) {
    __shared__ uint4 sB[2][4][2][64];    // [mat][nblk][kstep][lane]
    __shared__ float sb2[64];
    int tid = threadIdx.x;
    for (int i = tid; i < 1024; i += 256) {
        int mat = i >> 9, nb = (i >> 7) & 3, ks = (i >> 6) & 1, ln = i & 63;
        const float* W = mat ? W2r : W2l;
        int col = nb * 16 + (ln & 15);
        int kbase = ks * 32 + (ln >> 4) * 8;
        unsigned p0 = bf16pack2(W[(kbase + 0) * 64 + col], W[(kbase + 1) * 64 + col]);
        unsigned p1 = bf16pack2(W[(kbase + 2) * 64 + col], W[(kbase + 3) * 64 + col]);
        unsigned p2 = bf16pack2(W[(kbase + 4) * 64 + col], W[(kbase + 5) * 64 + col]);
        unsigned p3 = bf16pack2(W[(kbase + 6) * 64 + col], W[(kbase + 7) * 64 + col]);
        sB[mat][nb][ks][ln] = make_uint4(p0, p1, p2, p3);
    }
    if (tid < 64) sb2[tid] = b2[tid];
    __syncthreads();

    int w = tid >> 6, lane = tid & 63;
    int kg = lane >> 4;
    unsigned short* gh = (unsigned short*)g1p;
    unsigned short* rh = (unsigned short*)r1p;
    int ntile = (n_nodes + 63) >> 6;

    for (int t = blockIdx.x; t < ntile; t += gridDim.x) {
        int n0 = t << 6;
        int row = n0 + w * 16 + (lane & 15);
        int rowc = row < n_nodes ? row : n_nodes - 1;
        uint4 a0u = *(const uint4*)(h1p + (size_t)rowc * 32 + kg * 4);
        uint4 a1u = *(const uint4*)(h1p + (size_t)rowc * 32 + 16 + kg * 4);
        bf16x8 A0 = __builtin_bit_cast(bf16x8, a0u);
        bf16x8 A1 = __builtin_bit_cast(bf16x8, a1u);

        f32x4 accg[4], accr[4];
#pragma unroll
        for (int nb = 0; nb < 4; ++nb) {
            f32x4 z = {0.f, 0.f, 0.f, 0.f};
            bf16x8 Bg0 = __builtin_bit_cast(bf16x8, sB[0][nb][0][lane]);
            bf16x8 Bg1 = __builtin_bit_cast(bf16x8, sB[0][nb][1][lane]);
            bf16x8 Br0 = __builtin_bit_cast(bf16x8, sB[1][nb][0][lane]);
            bf16x8 Br1 = __builtin_bit_cast(bf16x8, sB[1][nb][1][lane]);
            accg[nb] = __builtin_amdgcn_mfma_f32_16x16x32_bf16(A0, Bg0, z, 0, 0, 0);
            accg[nb] = __builtin_amdgcn_mfma_f32_16x16x32_bf16(A1, Bg1, accg[nb], 0, 0, 0);
            accr[nb] = __builtin_amdgcn_mfma_f32_16x16x32_bf16(A0, Br0, z, 0, 0, 0);
            accr[nb] = __builtin_amdgcn_mfma_f32_16x16x32_bf16(A1, Br1, accr[nb], 0, 0, 0);
        }
        // C/D layout (verified, guide §3): col = lane&15, row = (lane>>4)*4 + reg
#pragma unroll
        for (int nb = 0; nb < 4; ++nb) {
            int col = nb * 16 + (lane & 15);
            float bias = sb2[col];
#pragma unroll
            for (int reg = 0; reg < 4; ++reg) {
                int r2 = n0 + w * 16 + kg * 4 + reg;
                if (r2 < n_nodes) {
                    gh[(size_t)r2 * 64 + col] = (unsigned short)bf16rn(accg[nb][reg]);
                    rh[(size_t)r2 * 64 + col] = (unsigned short)bf16rn(accr[nb][reg] + bias);
                }
            }
        }
    }
}

// conv2 aggregation + relu + W_out + pooling. R8 feature-pair scheme (proven
// 42us); r1p row load hoisted above the edge loop; NO cross-node prefetch
// (R14 lesson: it costs occupancy and regresses).
__global__ __launch_bounds__(256) void k_gather2(
    const int* __restrict__ csrp, const int* __restrict__ off,
    const int* __restrict__ deg_i, const float* __restrict__ inv,
    const unsigned* __restrict__ g1p, const unsigned* __restrict__ r1p,
    const int* __restrict__ batch, const float* __restrict__ Wout,
    float* __restrict__ outacc, float* __restrict__ cnt, int n_nodes) {
    int lane = threadIdx.x & 63;
    int li = lane & 31;                       // feature-pair index (uint in row)
    int hi = lane >> 5;                       // 0: even edges, 1: odd edges
    float hm = hi ? 0.f : 1.f;                // mask so halves don't double-count
    int w = blockIdx.x * 4 + (threadIdx.x >> 6);
    int nw = gridDim.x * 4;
    int per = (n_nodes + nw - 1) / nw;
    int n0 = w * per;
    int n1 = n0 + per; if (n1 > n_nodes) n1 = n_nodes;
    float4 wo = *(const float4*)(Wout + li * 4);   // W[2li][0..1], W[2li+1][0..1]
    float p0 = 0.f, p1 = 0.f, pc = 0.f;
    int curg = -1;
    for (int cb = n0; cb < n1; cb += 64) {
        int cn = n1 - cb; if (cn > 64) cn = 64;
        int voff = 0, vdeg = 0, vbat = 0; float vinv = 0.f;
        if (lane < cn) {
            voff = off[cb + lane]; vdeg = deg_i[cb + lane];
            vinv = inv[cb + lane]; vbat = batch[cb + lane];
        }
        for (int j = 0; j < cn; ++j) {
            int o = __shfl(voff, j), d = __shfl(vdeg, j), g = __shfl(vbat, j);
            float iv = __shfl(vinv, j);
            unsigned ur = r1p[(size_t)(cb + j) * 32 + li];   // hoisted (R12)
            float accL = 0.f, accH = 0.f;     // features 2li, 2li+1
            for (int base = 0; base < d; base += 64) {
                int rem = d - base; if (rem > 64) rem = 64;
                int v = (lane < rem) ? csrp[o + base + lane] : 0;
                int k = 0;
                int full8 = rem & ~7;
                for (; k < full8; k += 8) {   // 4 pairs = 8 edges, 4 loads in flight
                    int a0 = __shfl(v, k),     a1 = __shfl(v, k + 1);
                    int a2 = __shfl(v, k + 2), a3 = __shfl(v, k + 3);
                    int a4 = __shfl(v, k + 4), a5 = __shfl(v, k + 5);
                    int a6 = __shfl(v, k + 6), a7 = __shfl(v, k + 7);
                    size_t s0 = (size_t)((hi ? a1 : a0) & 0xFFFFF);
                    size_t s1 = (size_t)((hi ? a3 : a2) & 0xFFFFF);
                    size_t s2 = (size_t)((hi ? a5 : a4) & 0xFFFFF);
                    size_t s3 = (size_t)((hi ? a7 : a6) & 0xFFFFF);
                    unsigned u0 = g1p[s0 * 32 + li];
                    unsigned u1 = g1p[s1 * 32 + li];
                    unsigned u2 = g1p[s2 * 32 + li];
                    unsigned u3 = g1p[s3 * 32 + li];
                    accL += (__uint_as_float(u0 << 16) + __uint_as_float(u1 << 16)) +
                            (__uint_as_float(u2 << 16) + __uint_as_float(u3 << 16));
                    accH += (__uint_as_float(u0 & 0xFFFF0000u) + __uint_as_float(u1 & 0xFFFF0000u)) +
                            (__uint_as_float(u2 & 0xFFFF0000u) + __uint_as_float(u3 & 0xFFFF0000u));
                }
                for (; k + 1 < rem; k += 2) { // single pair
                    int a0 = __shfl(v, k), a1 = __shfl(v, k + 1);
                    size_t s = (size_t)((hi ? a1 : a0) & 0xFFFFF);
                    unsigned u = g1p[s * 32 + li];
                    accL += __uint_as_float(u << 16);
                    accH += __uint_as_float(u & 0xFFFF0000u);
                }
                if (k < rem) {                // odd tail: only hi==0 half counts
                    size_t s = (size_t)(__shfl(v, k) & 0xFFFFF);
                    unsigned u = g1p[s * 32 + li];
                    accL += hm * __uint_as_float(u << 16);
                    accH += hm * __uint_as_float(u & 0xFFFF0000u);
                }
            }
            accL += __shfl_xor(accL, 32);     // merge even/odd halves
            accH += __shfl_xor(accH, 32);
            float v0 = fmaxf(accL * iv + __uint_as_float(ur << 16), 0.f);
            float v1 = fmaxf(accH * iv + __uint_as_float(ur & 0xFFFF0000u), 0.f);
            if (g != curg) {                  // wave-uniform branch
                float q0 = p0, q1 = p1;
#pragma unroll
                for (int m = 1; m < 64; m <<= 1) { q0 += __shfl_xor(q0, m); q1 += __shfl_xor(q1, m); }
                if (lane == 0 && curg >= 0) {
                    atomicAdd(&outacc[curg * 2 + 0], q0);
                    atomicAdd(&outacc[curg * 2 + 1], q1);
                    atomicAdd(&cnt[curg], pc);
                }
                p0 = 0.f; p1 = 0.f; pc = 0.f; curg = g;
            }
            p0 += hm * (v0 * wo.x + v1 * wo.z);
            p1 += hm * (v0 * wo.y + v1 * wo.w);
            pc += 1.0f;
        }
    }
    {
        float q0 = p0, q1 = p1;
#pragma unroll
        for (int m = 1; m < 64; m <<= 1) { q0 += __shfl_xor(q0, m); q1 += __shfl_xor(q1, m); }
        if (lane == 0 && curg >= 0) {
            atomicAdd(&outacc[curg * 2 + 0], q0);
            atomicAdd(&outacc[curg * 2 + 1], q1);
            atomicAdd(&cnt[curg], pc);
        }
    }
}

__global__ void k_out(const float* __restrict__ outacc, const float* __restrict__ cnt,
                      const float* __restrict__ bout, float* __restrict__ out, int n_graphs) {
    int i = blockIdx.x * 256 + threadIdx.x;
    if (i < n_graphs * 2) {
        int g = i >> 1, c = i & 1;
        out[i] = outacc[i] / fmaxf(cnt[g], 1.0f) + bout[c];
    }
}

extern "C" void kernel_launch(void* const* d_in, const int* in_sizes, int n_in,
                              void* d_out, int out_size, void* d_ws, size_t ws_size,
                              hipStream_t stream) {
    const int* x     = (const int*)d_in[0];
    const int* ei    = (const int*)d_in[1];
    const int* batch = (const int*)d_in[2];
    const float* se   = (const float*)d_in[4];
    const float* ce   = (const float*)d_in[5];
    const float* Win  = (const float*)d_in[6];
    const float* bin  = (const float*)d_in[7];
    const float* W1l  = (const float*)d_in[8];
    const float* b1   = (const float*)d_in[9];
    const float* W1r  = (const float*)d_in[10];
    const float* W2l  = (const float*)d_in[11];
    const float* b2   = (const float*)d_in[12];
    const float* W2r  = (const float*)d_in[13];
    const float* Wout = (const float*)d_in[14];
    const float* bout = (const float*)d_in[15];
    float* out = (float*)d_out;

    int n_nodes  = in_sizes[0] / 2;
    int n_edges  = in_sizes[1] / 2;
    int n_graphs = out_size / 2;
    const int* src = ei;
    const int* dst = ei + n_edges;
    int nb = (n_nodes + 255) >> 8;               // buckets (<= 512 for n<131072)

    char* p = (char*)d_ws;
    auto take = [&](size_t bytes) { char* r = p; p += (bytes + 255) & ~(size_t)255; return r; };
    unsigned* h1p    = (unsigned*)take((size_t)n_nodes * 32 * 4);
    unsigned* g1p    = (unsigned*)take((size_t)n_nodes * 32 * 4);
    unsigned* r1p    = (unsigned*)take((size_t)n_nodes * 32 * 4);
    int*      csrp   = (int*)take((size_t)n_edges * 4);
    int*      bedge  = (int*)take((size_t)n_edges * 4);
    int*      ntype  = (int*)take((size_t)n_nodes * 4);
    int*      deg_i  = (int*)take((size_t)n_nodes * 4);
    int*      off    = (int*)take((size_t)n_nodes * 4);
    float*    inv    = (float*)take((size_t)n_nodes * 4);
    int*      histT  = (int*)take((size_t)512 * NBLK * 4);
    int*      blkOff = (int*)take((size_t)512 * NBLK * 4);
    int*      btot   = (int*)take(512 * 4);
    float*    cnt    = (float*)take((size_t)n_graphs * 4);
    float*    outacc = (float*)take((size_t)n_graphs * 8);
    float*    hltab  = (float*)take(4096 * 4);
    float*    hrtab  = (float*)take(4096 * 4);

    int nbN = (n_nodes + 255) / 256;

    k_front<<<NBLK + 64 + nbN, 256, 0, stream>>>(dst, histT, n_edges, nb,
                                                 se, ce, Win, bin, W1l, W1r, b1,
                                                 hltab, hrtab, x, ntype, cnt, outacc,
                                                 n_nodes, n_graphs);
    k_bscan<<<nb, 256, 0, stream>>>(histT, blkOff, btot);
    k_scatter<<<NBLK, 256, 0, stream>>>(src, dst, ntype, btot, blkOff, bedge, n_edges, nb);
    k_bsort<<<nb, 256, 0, stream>>>(bedge, btot, csrp, deg_i, off, inv, n_nodes, nb);
    k_gather1<<<2048, 256, 0, stream>>>(csrp, off, deg_i, inv, ntype, hltab, hrtab, h1p, n_nodes);
    k_lin2<<<1024, 256, 0, stream>>>(h1p, W2l, W2r, b2, g1p, r1p, n_nodes);
    k_gather2<<<2048, 256, 0, stream>>>(csrp, off, deg_i, inv, g1p, r1p, batch, Wout,
                                        outacc, cnt, n_nodes);
    k_out<<<(n_graphs * 2 + 255) / 256, 256, 0, stream>>>(outacc, cnt, bout, out, n_graphs);
}

// Round 16
// 128.872 us; speedup vs baseline: 1.1824x; 1.0339x over previous
//
#include <hip/hip_runtime.h>
#include <hip/hip_bf16.h>

// ---------------------------------------------------------------------------
// GNN classifier on MI355X.
//   h0 = relu([shape_emb[x0]|color_emb[x1]] @ W_in + b_in)   -> 64-entry table
//   conv1: h1 = relu( seg_sum(hltab[type[src]],dst)/deg + hrtab[type] )
//   conv2 by linearity:  g1 = h1@W2l, r1 = h1@W2r + b2  (bf16 MFMA GEMM)
//          h2 = relu( seg_sum(g1[src],dst)/deg + r1 )
//   out   = seg_sum(h2@W_out, batch)/cnt + b_out   (fused into the gather)
//
// R2: full-unroll spill lesson. R3: sorted batch -> deferred pooling flush.
// R4: no atomic-with-return on critical path. R5: coalesced edge loads +
// __shfl broadcast. R6: packed-bf16 intermediates halve gather traffic.
// R7: bucketed LDS sort replaces 1.2M device-scope atomics. R8: feature-pair
// lanes double gather2 MLP (42us @ occ 57%, VGPR 32 = its floor).
// R9: h1/r1 bf16; fused tab kernels. R10: MFMA lin2; 8 dispatches.
// R11: NBLK 256, gather1 ILP-8.
// R12/R14 LESSONS: both ILP-deepening attempts on gather2 regressed by
//      costing occupancy (16-edge loop: preamble; prefetch: VGPR 28->36).
//      Latency-bound gathers pay 1:1 in residency for per-wave live range.
// R15 (this round, from unblinded profile): gather1 = 42us at occupancy 31%
//      because 32KB LDS (two tables) caps blocks/CU; the per-node csrp L2
//      latency can't hide. Fix: stage only tl (16KB); read the per-node
//      hrtab row directly from global (16KB L2-resident, one coalesced 256B
//      read per node, issued before the edge loop so it's in flight).
// ---------------------------------------------------------------------------

#define NBLK 256   // blocks used by hist / scatter (chunked edge partition)

typedef __attribute__((ext_vector_type(8))) short bf16x8;
typedef __attribute__((ext_vector_type(4))) float f32x4;

__device__ __forceinline__ unsigned bf16rn(float x) {
    unsigned b = __float_as_uint(x);
    return (b + 0x7FFFu + ((b >> 16) & 1u)) >> 16;       // round-to-nearest-even
}
__device__ __forceinline__ unsigned bf16pack2(float lo, float hi) {
    return bf16rn(lo) | (bf16rn(hi) << 16);
}

// exclusive scan of btot[0..nb) into bb[0..512) (LDS), done by wave 0.
__device__ __forceinline__ void scan_btot(const int* __restrict__ btot, int nb,
                                          int* __restrict__ bb) {
    int tid = threadIdx.x;
    if (tid < 64) {
        int v[8]; int s = 0;
#pragma unroll
        for (int e = 0; e < 8; ++e) {
            int idx = tid * 8 + e;
            v[e] = s;
            s += (idx < nb) ? btot[idx] : 0;
        }
        int ex = s;
#pragma unroll
        for (int ofs = 1; ofs < 64; ofs <<= 1) {
            int t = __shfl_up(ex, ofs);
            if (tid >= ofs) ex += t;
        }
        ex -= s;                                  // exclusive prefix of lane sums
#pragma unroll
        for (int e = 0; e < 8; ++e) bb[tid * 8 + e] = ex + v[e];
    }
    __syncthreads();
}

// fused front-end: blocks [0,NBLK) histogram; [NBLK,NBLK+64) build tables;
// [NBLK+64, ...) ntype + accumulator zeroing. Disjoint roles, no stragglers.
__global__ __launch_bounds__(256) void k_front(
    const int* __restrict__ dst, int* __restrict__ histT, int n_edges, int nb,
    const float* __restrict__ se, const float* __restrict__ ce,
    const float* __restrict__ Win, const float* __restrict__ bin,
    const float* __restrict__ W1l, const float* __restrict__ W1r,
    const float* __restrict__ b1, float* __restrict__ hltab, float* __restrict__ hrtab,
    const int* __restrict__ x, int* __restrict__ ntype,
    float* __restrict__ cnt, float* __restrict__ outacc, int n_nodes, int n_graphs) {
    int blk = blockIdx.x, tid = threadIdx.x;
    if (blk < NBLK) {                                       // ---- histogram
        __shared__ int h[512];
        for (int i = tid; i < nb; i += 256) h[i] = 0;
        __syncthreads();
        int per = (n_edges + NBLK - 1) / NBLK;
        int e0 = blk * per;
        int e1 = e0 + per; if (e1 > n_edges) e1 = n_edges;
        for (int e = e0 + tid; e < e1; e += 256)
            atomicAdd(&h[dst[e] >> 8], 1);
        __syncthreads();
        for (int i = tid; i < nb; i += 256)
            histT[(size_t)i * NBLK + blk] = h[i];
    } else if (blk < NBLK + 64) {                           // ---- tables
        __shared__ float sse[64], sce[64], sh0[64];
        int t = blk - NBLK, j = tid;
        if (j < 64) {
            int s = t >> 3, c = t & 7;
            sse[j] = se[s * 64 + j];
            sce[j] = ce[c * 64 + j];
        }
        __syncthreads();
        if (j < 64) {
            float acc = bin[j];
            for (int k = 0; k < 64; ++k) {
                acc += sse[k] * Win[k * 64 + j];
                acc += sce[k] * Win[(64 + k) * 64 + j];
            }
            sh0[j] = fmaxf(acc, 0.f);
        }
        __syncthreads();
        if (j < 64) {
            float al = 0.f, ar = b1[j];
            for (int k = 0; k < 64; ++k) {
                float h = sh0[k];
                al += h * W1l[k * 64 + j];
                ar += h * W1r[k * 64 + j];
            }
            hltab[t * 64 + j] = al;
            hrtab[t * 64 + j] = ar;
        }
    } else {                                                // ---- prep + zero
        int n = (blk - NBLK - 64) * 256 + tid;
        if (n < n_nodes) {
            int2 v = *(const int2*)(x + 2 * (size_t)n);
            ntype[n] = v.x * 8 + v.y;
        }
        if (n < n_graphs) cnt[n] = 0.f;
        if (n < 2 * n_graphs) outacc[n] = 0.f;
    }
}

// per-bucket exclusive scan over the NBLK block counts (NBLK == 256).
__global__ __launch_bounds__(256) void k_bscan(const int* __restrict__ histT,
                                               int* __restrict__ blockOff,
                                               int* __restrict__ btot) {
    __shared__ int sbuf[2][256];
    int b = blockIdx.x, tid = threadIdx.x;
    int d = histT[(size_t)b * NBLK + tid];
    int cur = 0;
    sbuf[0][tid] = d;
    __syncthreads();
    for (int ofs = 1; ofs < 256; ofs <<= 1) {
        int v = sbuf[cur][tid];
        if (tid >= ofs) v += sbuf[cur][tid - ofs];
        sbuf[cur ^ 1][tid] = v;
        cur ^= 1;
        __syncthreads();
    }
    blockOff[(size_t)b * NBLK + tid] = sbuf[cur][tid] - d;
    if (tid == 255) btot[b] = sbuf[cur][tid];
}

// scatter edges into bucket-grouped order; bucket bases recomputed locally.
__global__ __launch_bounds__(256) void k_scatter(
    const int* __restrict__ src, const int* __restrict__ dst,
    const int* __restrict__ ntype, const int* __restrict__ btot,
    const int* __restrict__ blockOff, int* __restrict__ bedge,
    int n_edges, int nb) {
    __shared__ int bb[512];
    __shared__ int cur[512];
    int tid = threadIdx.x, blk = blockIdx.x;
    scan_btot(btot, nb, bb);
    for (int i = tid; i < nb; i += 256)
        cur[i] = bb[i] + blockOff[(size_t)i * NBLK + blk];
    __syncthreads();
    int per = (n_edges + NBLK - 1) / NBLK;
    int e0 = blk * per;
    int e1 = e0 + per; if (e1 > n_edges) e1 = n_edges;
    for (int e = e0 + tid; e < e1; e += 256) {
        int d = dst[e], s = src[e];
        int pos = atomicAdd(&cur[d >> 8], 1);       // LDS atomic (fast)
        bedge[pos] = s | (ntype[s] << 17) | ((d & 255) << 23);
    }
}

// per-bucket 256-way counting sort in LDS; emits deg/off/inv + final csrp.
__global__ __launch_bounds__(256) void k_bsort(
    const int* __restrict__ bedge, const int* __restrict__ btot,
    int* __restrict__ csrp, int* __restrict__ deg, int* __restrict__ off,
    float* __restrict__ inv, int n_nodes, int nb) {
    __shared__ int bb[512];
    __shared__ int cnt[256];
    __shared__ int sbuf[2][256];
    __shared__ int loff[256];
    int b = blockIdx.x, tid = threadIdx.x;
    scan_btot(btot, nb, bb);
    int base = bb[b], tot = btot[b];
    cnt[tid] = 0;
    __syncthreads();
    for (int i = tid; i < tot; i += 256)
        atomicAdd(&cnt[(bedge[base + i] >> 23) & 255], 1);
    __syncthreads();
    int d = cnt[tid];
    int cur = 0;
    sbuf[0][tid] = d;
    __syncthreads();
    for (int ofs = 1; ofs < 256; ofs <<= 1) {
        int v = sbuf[cur][tid];
        if (tid >= ofs) v += sbuf[cur][tid - ofs];
        sbuf[cur ^ 1][tid] = v;
        cur ^= 1;
        __syncthreads();
    }
    loff[tid] = sbuf[cur][tid] - d;                  // exclusive within bucket
    __syncthreads();
    int n = b * 256 + tid;
    if (n < n_nodes) {
        deg[n] = d;
        off[n] = base + loff[tid];
        inv[n] = 1.0f / fmaxf((float)d, 1.0f);
    }
    cnt[tid] = loff[tid];                            // reuse as cursor
    __syncthreads();
    for (int i = tid; i < tot; i += 256) {
        int v = bedge[base + i];
        int pos = atomicAdd(&cnt[(v >> 23) & 255], 1);
        csrp[base + pos] = (v & 0x1FFFF) | (((v >> 17) & 63) << 20);
    }
}

// ---- compute kernels --------------------------------------------------------

// conv1; h1 written as PACKED BF16 rows. ILP-8 LDS chain. R15: only tl staged
// in LDS (16KB -> 2x block residency); per-node hrtab row read from global
// (L2-resident), issued before the edge loop so it overlaps.
__global__ __launch_bounds__(256) void k_gather1(
    const int* __restrict__ csrp, const int* __restrict__ off,
    const int* __restrict__ deg_i, const float* __restrict__ inv,
    const int* __restrict__ ntype, const float* __restrict__ hltab,
    const float* __restrict__ hrtab, unsigned* __restrict__ h1p, int n_nodes) {
    __shared__ float tl[4096];
    for (int i = threadIdx.x; i < 4096; i += 256) tl[i] = hltab[i];
    __syncthreads();
    int lane = threadIdx.x & 63;
    int w = blockIdx.x * 4 + (threadIdx.x >> 6);
    int nw = gridDim.x * 4;
    int per = (n_nodes + nw - 1) / nw;
    int n0 = w * per;
    int n1 = n0 + per; if (n1 > n_nodes) n1 = n_nodes;
    for (int cb = n0; cb < n1; cb += 64) {
        int cn = n1 - cb; if (cn > 64) cn = 64;
        int voff = 0, vdeg = 0, vnt = 0; float vinv = 0.f;
        if (lane < cn) {
            voff = off[cb + lane]; vdeg = deg_i[cb + lane];
            vinv = inv[cb + lane]; vnt  = ntype[cb + lane];
        }
        for (int j = 0; j < cn; ++j) {
            int o = __shfl(voff, j), d = __shfl(vdeg, j);
            float iv = __shfl(vinv, j);
            int tn = __shfl(vnt, j);
            float rv = hrtab[tn * 64 + lane];   // global, L2-hit; in flight below
            float acc = 0.f;
            for (int base = 0; base < d; base += 64) {
                int rem = d - base; if (rem > 64) rem = 64;
                int v = (lane < rem) ? csrp[o + base + lane] : 0;
                int k = 0;
                int full8 = rem & ~7;
                for (; k < full8; k += 8) {
                    float s0 = tl[(__shfl(v, k)     >> 20) * 64 + lane];
                    float s1 = tl[(__shfl(v, k + 1) >> 20) * 64 + lane];
                    float s2 = tl[(__shfl(v, k + 2) >> 20) * 64 + lane];
                    float s3 = tl[(__shfl(v, k + 3) >> 20) * 64 + lane];
                    float s4 = tl[(__shfl(v, k + 4) >> 20) * 64 + lane];
                    float s5 = tl[(__shfl(v, k + 5) >> 20) * 64 + lane];
                    float s6 = tl[(__shfl(v, k + 6) >> 20) * 64 + lane];
                    float s7 = tl[(__shfl(v, k + 7) >> 20) * 64 + lane];
                    acc += ((s0 + s1) + (s2 + s3)) + ((s4 + s5) + (s6 + s7));
                }
                for (; k < rem; ++k)
                    acc += tl[(__shfl(v, k) >> 20) * 64 + lane];
            }
            float val = fmaxf(acc * iv + rv, 0.f);
            float vhi = __shfl_down(val, 1);
            if (!(lane & 1))
                h1p[(size_t)(cb + j) * 32 + (lane >> 1)] = bf16pack2(val, vhi);
        }
    }
}

// conv2 dense GEMMs on MFMA bf16 (R10): g1 = h1@W2l, r1 = h1@W2r + b2.
__global__ __launch_bounds__(256) void k_lin2(
    const unsigned* __restrict__ h1p, const float* __restrict__ W2l,
    const float* __restrict__ W2r, const float* __restrict__ b2,
    unsigned* __restrict__ g1p, unsigned* __restrict__ r1p, int n_nodes) {
    __shared__ uint4 sB[2][4][2][64];    // [mat][nblk][kstep][lane]
    __shared__ float sb2[64];
    int tid = threadIdx.x;
    for (int i = tid; i < 1024; i += 256) {
        int mat = i >> 9, nb = (i >> 7) & 3, ks = (i >> 6) & 1, ln = i & 63;
        const float* W = mat ? W2r : W2l;
        int col = nb * 16 + (ln & 15);
        int kbase = ks * 32 + (ln >> 4) * 8;
        unsigned p0 = bf16pack2(W[(kbase + 0) * 64 + col], W[(kbase + 1) * 64 + col]);
        unsigned p1 = bf16pack2(W[(kbase + 2) * 64 + col], W[(kbase + 3) * 64 + col]);
        unsigned p2 = bf16pack2(W[(kbase + 4) * 64 + col], W[(kbase + 5) * 64 + col]);
        unsigned p3 = bf16pack2(W[(kbase + 6) * 64 + col], W[(kbase + 7) * 64 + col]);
        sB[mat][nb][ks][ln] = make_uint4(p0, p1, p2, p3);
    }
    if (tid < 64) sb2[tid] = b2[tid];
    __syncthreads();

    int w = tid >> 6, lane = tid & 63;
    int kg = lane >> 4;
    unsigned short* gh = (unsigned short*)g1p;
    unsigned short* rh = (unsigned short*)r1p;
    int ntile = (n_nodes + 63) >> 6;

    for (int t = blockIdx.x; t < ntile; t += gridDim.x) {
        int n0 = t << 6;
        int row = n0 + w * 16 + (lane & 15);
        int rowc = row < n_nodes ? row : n_nodes - 1;
        uint4 a0u = *(const uint4*)(h1p + (size_t)rowc * 32 + kg * 4);
        uint4 a1u = *(const uint4*)(h1p + (size_t)rowc * 32 + 16 + kg * 4);
        bf16x8 A0 = __builtin_bit_cast(bf16x8, a0u);
        bf16x8 A1 = __builtin_bit_cast(bf16x8, a1u);

        f32x4 accg[4], accr[4];
#pragma unroll
        for (int nb = 0; nb < 4; ++nb) {
            f32x4 z = {0.f, 0.f, 0.f, 0.f};
            bf16x8 Bg0 = __builtin_bit_cast(bf16x8, sB[0][nb][0][lane]);
            bf16x8 Bg1 = __builtin_bit_cast(bf16x8, sB[0][nb][1][lane]);
            bf16x8 Br0 = __builtin_bit_cast(bf16x8, sB[1][nb][0][lane]);
            bf16x8 Br1 = __builtin_bit_cast(bf16x8, sB[1][nb][1][lane]);
            accg[nb] = __builtin_amdgcn_mfma_f32_16x16x32_bf16(A0, Bg0, z, 0, 0, 0);
            accg[nb] = __builtin_amdgcn_mfma_f32_16x16x32_bf16(A1, Bg1, accg[nb], 0, 0, 0);
            accr[nb] = __builtin_amdgcn_mfma_f32_16x16x32_bf16(A0, Br0, z, 0, 0, 0);
            accr[nb] = __builtin_amdgcn_mfma_f32_16x16x32_bf16(A1, Br1, accr[nb], 0, 0, 0);
        }
        // C/D layout (verified, guide §3): col = lane&15, row = (lane>>4)*4 + reg
#pragma unroll
        for (int nb = 0; nb < 4; ++nb) {
            int col = nb * 16 + (lane & 15);
            float bias = sb2[col];
#pragma unroll
            for (int reg = 0; reg < 4; ++reg) {
                int r2 = n0 + w * 16 + kg * 4 + reg;
                if (r2 < n_nodes) {
                    gh[(size_t)r2 * 64 + col] = (unsigned short)bf16rn(accg[nb][reg]);
                    rh[(size_t)r2 * 64 + col] = (unsigned short)bf16rn(accr[nb][reg] + bias);
                }
            }
        }
    }
}

// conv2 aggregation + relu + W_out + pooling. R8 feature-pair scheme (proven
// 42us floor); r1p row load hoisted; NO cross-node prefetch (R14 lesson).
__global__ __launch_bounds__(256) void k_gather2(
    const int* __restrict__ csrp, const int* __restrict__ off,
    const int* __restrict__ deg_i, const float* __restrict__ inv,
    const unsigned* __restrict__ g1p, const unsigned* __restrict__ r1p,
    const int* __restrict__ batch, const float* __restrict__ Wout,
    float* __restrict__ outacc, float* __restrict__ cnt, int n_nodes) {
    int lane = threadIdx.x & 63;
    int li = lane & 31;                       // feature-pair index (uint in row)
    int hi = lane >> 5;                       // 0: even edges, 1: odd edges
    float hm = hi ? 0.f : 1.f;                // mask so halves don't double-count
    int w = blockIdx.x * 4 + (threadIdx.x >> 6);
    int nw = gridDim.x * 4;
    int per = (n_nodes + nw - 1) / nw;
    int n0 = w * per;
    int n1 = n0 + per; if (n1 > n_nodes) n1 = n_nodes;
    float4 wo = *(const float4*)(Wout + li * 4);   // W[2li][0..1], W[2li+1][0..1]
    float p0 = 0.f, p1 = 0.f, pc = 0.f;
    int curg = -1;
    for (int cb = n0; cb < n1; cb += 64) {
        int cn = n1 - cb; if (cn > 64) cn = 64;
        int voff = 0, vdeg = 0, vbat = 0; float vinv = 0.f;
        if (lane < cn) {
            voff = off[cb + lane]; vdeg = deg_i[cb + lane];
            vinv = inv[cb + lane]; vbat = batch[cb + lane];
        }
        for (int j = 0; j < cn; ++j) {
            int o = __shfl(voff, j), d = __shfl(vdeg, j), g = __shfl(vbat, j);
            float iv = __shfl(vinv, j);
            unsigned ur = r1p[(size_t)(cb + j) * 32 + li];   // hoisted (R12)
            float accL = 0.f, accH = 0.f;     // features 2li, 2li+1
            for (int base = 0; base < d; base += 64) {
                int rem = d - base; if (rem > 64) rem = 64;
                int v = (lane < rem) ? csrp[o + base + lane] : 0;
                int k = 0;
                int full8 = rem & ~7;
                for (; k < full8; k += 8) {   // 4 pairs = 8 edges, 4 loads in flight
                    int a0 = __shfl(v, k),     a1 = __shfl(v, k + 1);
                    int a2 = __shfl(v, k + 2), a3 = __shfl(v, k + 3);
                    int a4 = __shfl(v, k + 4), a5 = __shfl(v, k + 5);
                    int a6 = __shfl(v, k + 6), a7 = __shfl(v, k + 7);
                    size_t s0 = (size_t)((hi ? a1 : a0) & 0xFFFFF);
                    size_t s1 = (size_t)((hi ? a3 : a2) & 0xFFFFF);
                    size_t s2 = (size_t)((hi ? a5 : a4) & 0xFFFFF);
                    size_t s3 = (size_t)((hi ? a7 : a6) & 0xFFFFF);
                    unsigned u0 = g1p[s0 * 32 + li];
                    unsigned u1 = g1p[s1 * 32 + li];
                    unsigned u2 = g1p[s2 * 32 + li];
                    unsigned u3 = g1p[s3 * 32 + li];
                    accL += (__uint_as_float(u0 << 16) + __uint_as_float(u1 << 16)) +
                            (__uint_as_float(u2 << 16) + __uint_as_float(u3 << 16));
                    accH += (__uint_as_float(u0 & 0xFFFF0000u) + __uint_as_float(u1 & 0xFFFF0000u)) +
                            (__uint_as_float(u2 & 0xFFFF0000u) + __uint_as_float(u3 & 0xFFFF0000u));
                }
                for (; k + 1 < rem; k += 2) { // single pair
                    int a0 = __shfl(v, k), a1 = __shfl(v, k + 1);
                    size_t s = (size_t)((hi ? a1 : a0) & 0xFFFFF);
                    unsigned u = g1p[s * 32 + li];
                    accL += __uint_as_float(u << 16);
                    accH += __uint_as_float(u & 0xFFFF0000u);
                }
                if (k < rem) {                // odd tail: only hi==0 half counts
                    size_t s = (size_t)(__shfl(v, k) & 0xFFFFF);
                    unsigned u = g1p[s * 32 + li];
                    accL += hm * __uint_as_float(u << 16);
                    accH += hm * __uint_as_float(u & 0xFFFF0000u);
                }
            }
            accL += __shfl_xor(accL, 32);     // merge even/odd halves
            accH += __shfl_xor(accH, 32);
            float v0 = fmaxf(accL * iv + __uint_as_float(ur << 16), 0.f);
            float v1 = fmaxf(accH * iv + __uint_as_float(ur & 0xFFFF0000u), 0.f);
            if (g != curg) {                  // wave-uniform branch
                float q0 = p0, q1 = p1;
#pragma unroll
                for (int m = 1; m < 64; m <<= 1) { q0 += __shfl_xor(q0, m); q1 += __shfl_xor(q1, m); }
                if (lane == 0 && curg >= 0) {
                    atomicAdd(&outacc[curg * 2 + 0], q0);
                    atomicAdd(&outacc[curg * 2 + 1], q1);
                    atomicAdd(&cnt[curg], pc);
                }
                p0 = 0.f; p1 = 0.f; pc = 0.f; curg = g;
            }
            p0 += hm * (v0 * wo.x + v1 * wo.z);
            p1 += hm * (v0 * wo.y + v1 * wo.w);
            pc += 1.0f;
        }
    }
    {
        float q0 = p0, q1 = p1;
#pragma unroll
        for (int m = 1; m < 64; m <<= 1) { q0 += __shfl_xor(q0, m); q1 += __shfl_xor(q1, m); }
        if (lane == 0 && curg >= 0) {
            atomicAdd(&outacc[curg * 2 + 0], q0);
            atomicAdd(&outacc[curg * 2 + 1], q1);
            atomicAdd(&cnt[curg], pc);
        }
    }
}

__global__ void k_out(const float* __restrict__ outacc, const float* __restrict__ cnt,
                      const float* __restrict__ bout, float* __restrict__ out, int n_graphs) {
    int i = blockIdx.x * 256 + threadIdx.x;
    if (i < n_graphs * 2) {
        int g = i >> 1, c = i & 1;
        out[i] = outacc[i] / fmaxf(cnt[g], 1.0f) + bout[c];
    }
}

extern "C" void kernel_launch(void* const* d_in, const int* in_sizes, int n_in,
                              void* d_out, int out_size, void* d_ws, size_t ws_size,
                              hipStream_t stream) {
    const int* x     = (const int*)d_in[0];
    const int* ei    = (const int*)d_in[1];
    const int* batch = (const int*)d_in[2];
    const float* se   = (const float*)d_in[4];
    const float* ce   = (const float*)d_in[5];
    const float* Win  = (const float*)d_in[6];
    const float* bin  = (const float*)d_in[7];
    const float* W1l  = (const float*)d_in[8];
    const float* b1   = (const float*)d_in[9];
    const float* W1r  = (const float*)d_in[10];
    const float* W2l  = (const float*)d_in[11];
    const float* b2   = (const float*)d_in[12];
    const float* W2r  = (const float*)d_in[13];
    const float* Wout = (const float*)d_in[14];
    const float* bout = (const float*)d_in[15];
    float* out = (float*)d_out;

    int n_nodes  = in_sizes[0] / 2;
    int n_edges  = in_sizes[1] / 2;
    int n_graphs = out_size / 2;
    const int* src = ei;
    const int* dst = ei + n_edges;
    int nb = (n_nodes + 255) >> 8;               // buckets (<= 512 for n<131072)

    char* p = (char*)d_ws;
    auto take = [&](size_t bytes) { char* r = p; p += (bytes + 255) & ~(size_t)255; return r; };
    unsigned* h1p    = (unsigned*)take((size_t)n_nodes * 32 * 4);
    unsigned* g1p    = (unsigned*)take((size_t)n_nodes * 32 * 4);
    unsigned* r1p    = (unsigned*)take((size_t)n_nodes * 32 * 4);
    int*      csrp   = (int*)take((size_t)n_edges * 4);
    int*      bedge  = (int*)take((size_t)n_edges * 4);
    int*      ntype  = (int*)take((size_t)n_nodes * 4);
    int*      deg_i  = (int*)take((size_t)n_nodes * 4);
    int*      off    = (int*)take((size_t)n_nodes * 4);
    float*    inv    = (float*)take((size_t)n_nodes * 4);
    int*      histT  = (int*)take((size_t)512 * NBLK * 4);
    int*      blkOff = (int*)take((size_t)512 * NBLK * 4);
    int*      btot   = (int*)take(512 * 4);
    float*    cnt    = (float*)take((size_t)n_graphs * 4);
    float*    outacc = (float*)take((size_t)n_graphs * 8);
    float*    hltab  = (float*)take(4096 * 4);
    float*    hrtab  = (float*)take(4096 * 4);

    int nbN = (n_nodes + 255) / 256;

    k_front<<<NBLK + 64 + nbN, 256, 0, stream>>>(dst, histT, n_edges, nb,
                                                 se, ce, Win, bin, W1l, W1r, b1,
                                                 hltab, hrtab, x, ntype, cnt, outacc,
                                                 n_nodes, n_graphs);
    k_bscan<<<nb, 256, 0, stream>>>(histT, blkOff, btot);
    k_scatter<<<NBLK, 256, 0, stream>>>(src, dst, ntype, btot, blkOff, bedge, n_edges, nb);
    k_bsort<<<nb, 256, 0, stream>>>(bedge, btot, csrp, deg_i, off, inv, n_nodes, nb);
    k_gather1<<<2048, 256, 0, stream>>>(csrp, off, deg_i, inv, ntype, hltab, hrtab, h1p, n_nodes);
    k_lin2<<<1024, 256, 0, stream>>>(h1p, W2l, W2r, b2, g1p, r1p, n_nodes);
    k_gather2<<<2048, 256, 0, stream>>>(csrp, off, deg_i, inv, g1p, r1p, batch, Wout,
                                        outacc, cnt, n_nodes);
    k_out<<<(n_graphs * 2 + 255) / 256, 256, 0, stream>>>(outacc, cnt, bout, out, n_graphs);
}

// Round 17
// 122.328 us; speedup vs baseline: 1.2456x; 1.0535x over previous
//
#include <hip/hip_runtime.h>
#include <hip/hip_bf16.h>

// ---------------------------------------------------------------------------
// GNN classifier on MI355X.
//   h0 = relu([shape_emb[x0]|color_emb[x1]] @ W_in + b_in)   -> 64-entry table
//   conv1: h1 = relu( seg_sum(hltab[type[src]],dst)/deg + hrtab[type] )
//   conv2 by linearity:  g1 = h1@W2l, r1 = h1@W2r + b2  (bf16 MFMA GEMM)
//          h2 = relu( seg_sum(g1[src],dst)/deg + r1 )
//   out   = seg_sum(h2@W_out, batch)/cnt + b_out   (fused into the gather)
//
// R2: full-unroll spill lesson. R3: sorted batch -> deferred pooling flush.
// R4: no atomic-with-return on critical path. R5: coalesced edge loads +
// __shfl broadcast. R6: packed-bf16 intermediates halve gather traffic.
// R7: bucketed LDS sort replaces 1.2M device-scope atomics. R8: feature-pair
// lanes double gather2 MLP (42us @ occ 57%, VGPR 32 = its floor).
// R9: h1/r1 bf16; fused tab kernels. R10: MFMA lin2; 8 dispatches.
// R12/R14 LESSONS: per-wave ILP via longer live ranges regresses (occupancy
//      pays 1:1). R15: gather1 LDS 32->16KB helped only 4us -> the real cost
//      is the PER-NODE SERIAL csrp L2 load (~400cy x 12 nodes/wave).
// R16 (this round): off[] is globally contiguous (bucketed sort invariant:
//      off[n+1]=off[n]+deg[n]), so a wave's 32-node chunk owns ONE contiguous
//      csrp range (~384 edges). Stage it with 8 independent coalesced loads
//      (all in flight; registers->LDS, VGPR stays <64) then run the edge loop
//      entirely from LDS broadcasts. 12 serial round-trips -> 1. Fallback to
//      the direct path if a chunk exceeds 512 edges. gather2 untouched.
// ---------------------------------------------------------------------------

#define NBLK 256   // blocks used by hist / scatter (chunked edge partition)

typedef __attribute__((ext_vector_type(8))) short bf16x8;
typedef __attribute__((ext_vector_type(4))) float f32x4;

__device__ __forceinline__ unsigned bf16rn(float x) {
    unsigned b = __float_as_uint(x);
    return (b + 0x7FFFu + ((b >> 16) & 1u)) >> 16;       // round-to-nearest-even
}
__device__ __forceinline__ unsigned bf16pack2(float lo, float hi) {
    return bf16rn(lo) | (bf16rn(hi) << 16);
}

// exclusive scan of btot[0..nb) into bb[0..512) (LDS), done by wave 0.
__device__ __forceinline__ void scan_btot(const int* __restrict__ btot, int nb,
                                          int* __restrict__ bb) {
    int tid = threadIdx.x;
    if (tid < 64) {
        int v[8]; int s = 0;
#pragma unroll
        for (int e = 0; e < 8; ++e) {
            int idx = tid * 8 + e;
            v[e] = s;
            s += (idx < nb) ? btot[idx] : 0;
        }
        int ex = s;
#pragma unroll
        for (int ofs = 1; ofs < 64; ofs <<= 1) {
            int t = __shfl_up(ex, ofs);
            if (tid >= ofs) ex += t;
        }
        ex -= s;                                  // exclusive prefix of lane sums
#pragma unroll
        for (int e = 0; e < 8; ++e) bb[tid * 8 + e] = ex + v[e];
    }
    __syncthreads();
}

// fused front-end: blocks [0,NBLK) histogram; [NBLK,NBLK+64) build tables;
// [NBLK+64, ...) ntype + accumulator zeroing. Disjoint roles, no stragglers.
__global__ __launch_bounds__(256) void k_front(
    const int* __restrict__ dst, int* __restrict__ histT, int n_edges, int nb,
    const float* __restrict__ se, const float* __restrict__ ce,
    const float* __restrict__ Win, const float* __restrict__ bin,
    const float* __restrict__ W1l, const float* __restrict__ W1r,
    const float* __restrict__ b1, float* __restrict__ hltab, float* __restrict__ hrtab,
    const int* __restrict__ x, int* __restrict__ ntype,
    float* __restrict__ cnt, float* __restrict__ outacc, int n_nodes, int n_graphs) {
    int blk = blockIdx.x, tid = threadIdx.x;
    if (blk < NBLK) {                                       // ---- histogram
        __shared__ int h[512];
        for (int i = tid; i < nb; i += 256) h[i] = 0;
        __syncthreads();
        int per = (n_edges + NBLK - 1) / NBLK;
        int e0 = blk * per;
        int e1 = e0 + per; if (e1 > n_edges) e1 = n_edges;
        for (int e = e0 + tid; e < e1; e += 256)
            atomicAdd(&h[dst[e] >> 8], 1);
        __syncthreads();
        for (int i = tid; i < nb; i += 256)
            histT[(size_t)i * NBLK + blk] = h[i];
    } else if (blk < NBLK + 64) {                           // ---- tables
        __shared__ float sse[64], sce[64], sh0[64];
        int t = blk - NBLK, j = tid;
        if (j < 64) {
            int s = t >> 3, c = t & 7;
            sse[j] = se[s * 64 + j];
            sce[j] = ce[c * 64 + j];
        }
        __syncthreads();
        if (j < 64) {
            float acc = bin[j];
            for (int k = 0; k < 64; ++k) {
                acc += sse[k] * Win[k * 64 + j];
                acc += sce[k] * Win[(64 + k) * 64 + j];
            }
            sh0[j] = fmaxf(acc, 0.f);
        }
        __syncthreads();
        if (j < 64) {
            float al = 0.f, ar = b1[j];
            for (int k = 0; k < 64; ++k) {
                float h = sh0[k];
                al += h * W1l[k * 64 + j];
                ar += h * W1r[k * 64 + j];
            }
            hltab[t * 64 + j] = al;
            hrtab[t * 64 + j] = ar;
        }
    } else {                                                // ---- prep + zero
        int n = (blk - NBLK - 64) * 256 + tid;
        if (n < n_nodes) {
            int2 v = *(const int2*)(x + 2 * (size_t)n);
            ntype[n] = v.x * 8 + v.y;
        }
        if (n < n_graphs) cnt[n] = 0.f;
        if (n < 2 * n_graphs) outacc[n] = 0.f;
    }
}

// per-bucket exclusive scan over the NBLK block counts (NBLK == 256).
__global__ __launch_bounds__(256) void k_bscan(const int* __restrict__ histT,
                                               int* __restrict__ blockOff,
                                               int* __restrict__ btot) {
    __shared__ int sbuf[2][256];
    int b = blockIdx.x, tid = threadIdx.x;
    int d = histT[(size_t)b * NBLK + tid];
    int cur = 0;
    sbuf[0][tid] = d;
    __syncthreads();
    for (int ofs = 1; ofs < 256; ofs <<= 1) {
        int v = sbuf[cur][tid];
        if (tid >= ofs) v += sbuf[cur][tid - ofs];
        sbuf[cur ^ 1][tid] = v;
        cur ^= 1;
        __syncthreads();
    }
    blockOff[(size_t)b * NBLK + tid] = sbuf[cur][tid] - d;
    if (tid == 255) btot[b] = sbuf[cur][tid];
}

// scatter edges into bucket-grouped order; bucket bases recomputed locally.
__global__ __launch_bounds__(256) void k_scatter(
    const int* __restrict__ src, const int* __restrict__ dst,
    const int* __restrict__ ntype, const int* __restrict__ btot,
    const int* __restrict__ blockOff, int* __restrict__ bedge,
    int n_edges, int nb) {
    __shared__ int bb[512];
    __shared__ int cur[512];
    int tid = threadIdx.x, blk = blockIdx.x;
    scan_btot(btot, nb, bb);
    for (int i = tid; i < nb; i += 256)
        cur[i] = bb[i] + blockOff[(size_t)i * NBLK + blk];
    __syncthreads();
    int per = (n_edges + NBLK - 1) / NBLK;
    int e0 = blk * per;
    int e1 = e0 + per; if (e1 > n_edges) e1 = n_edges;
    for (int e = e0 + tid; e < e1; e += 256) {
        int d = dst[e], s = src[e];
        int pos = atomicAdd(&cur[d >> 8], 1);       // LDS atomic (fast)
        bedge[pos] = s | (ntype[s] << 17) | ((d & 255) << 23);
    }
}

// per-bucket 256-way counting sort in LDS; emits deg/off/inv + final csrp.
__global__ __launch_bounds__(256) void k_bsort(
    const int* __restrict__ bedge, const int* __restrict__ btot,
    int* __restrict__ csrp, int* __restrict__ deg, int* __restrict__ off,
    float* __restrict__ inv, int n_nodes, int nb) {
    __shared__ int bb[512];
    __shared__ int cnt[256];
    __shared__ int sbuf[2][256];
    __shared__ int loff[256];
    int b = blockIdx.x, tid = threadIdx.x;
    scan_btot(btot, nb, bb);
    int base = bb[b], tot = btot[b];
    cnt[tid] = 0;
    __syncthreads();
    for (int i = tid; i < tot; i += 256)
        atomicAdd(&cnt[(bedge[base + i] >> 23) & 255], 1);
    __syncthreads();
    int d = cnt[tid];
    int cur = 0;
    sbuf[0][tid] = d;
    __syncthreads();
    for (int ofs = 1; ofs < 256; ofs <<= 1) {
        int v = sbuf[cur][tid];
        if (tid >= ofs) v += sbuf[cur][tid - ofs];
        sbuf[cur ^ 1][tid] = v;
        cur ^= 1;
        __syncthreads();
    }
    loff[tid] = sbuf[cur][tid] - d;                  // exclusive within bucket
    __syncthreads();
    int n = b * 256 + tid;
    if (n < n_nodes) {
        deg[n] = d;
        off[n] = base + loff[tid];
        inv[n] = 1.0f / fmaxf((float)d, 1.0f);
    }
    cnt[tid] = loff[tid];                            // reuse as cursor
    __syncthreads();
    for (int i = tid; i < tot; i += 256) {
        int v = bedge[base + i];
        int pos = atomicAdd(&cnt[(v >> 23) & 255], 1);
        csrp[base + pos] = (v & 0x1FFFF) | (((v >> 17) & 63) << 20);
    }
}

// ---- compute kernels --------------------------------------------------------

// conv1; h1 written as PACKED BF16 rows. R16: per-wave 32-node chunks; the
// chunk's CONTIGUOUS csrp range is staged into LDS with 8 independent
// coalesced loads (registers->LDS), then the edge loop runs from LDS
// broadcasts only. Fallback to direct loads if a chunk exceeds 512 edges.
__global__ __launch_bounds__(256) void k_gather1(
    const int* __restrict__ csrp, const int* __restrict__ off,
    const int* __restrict__ deg_i, const float* __restrict__ inv,
    const int* __restrict__ ntype, const float* __restrict__ hltab,
    const float* __restrict__ hrtab, unsigned* __restrict__ h1p, int n_nodes) {
    __shared__ float tl[4096];           // 16 KB conv1 message table
    __shared__ int ebuf[4][512];         // 8 KB per-wave staged edge buffers
    for (int i = threadIdx.x; i < 4096; i += 256) tl[i] = hltab[i];
    __syncthreads();
    int lane = threadIdx.x & 63;
    int wv = threadIdx.x >> 6;
    int* buf = ebuf[wv];
    int w = blockIdx.x * 4 + wv;
    int nw = gridDim.x * 4;
    int per = (n_nodes + nw - 1) / nw;
    int n0 = w * per;
    int n1 = n0 + per; if (n1 > n_nodes) n1 = n_nodes;
    for (int cb = n0; cb < n1; cb += 32) {
        int cn = n1 - cb; if (cn > 32) cn = 32;
        int voff = 0, vdeg = 0, vnt = 0; float vinv = 0.f;
        if (lane < cn) {
            voff = off[cb + lane]; vdeg = deg_i[cb + lane];
            vinv = inv[cb + lane]; vnt  = ntype[cb + lane];
        }
        int o0  = __shfl(voff, 0);
        int tot = __shfl(voff + vdeg, cn - 1) - o0;   // contiguous CSR range
        if (tot <= 512) {
            // stage: 8 independent coalesced loads, then 8 LDS writes
            int vv[8];
#pragma unroll
            for (int e = 0; e < 8; ++e) {
                int i = lane + e * 64;
                vv[e] = (i < tot) ? csrp[o0 + i] : 0;
            }
#pragma unroll
            for (int e = 0; e < 8; ++e)
                buf[lane + e * 64] = vv[e];
            __builtin_amdgcn_wave_barrier();          // order LDS ops (free)
            for (int j = 0; j < cn; ++j) {
                int eb = __shfl(voff, j) - o0, d = __shfl(vdeg, j);
                float iv = __shfl(vinv, j);
                int tn = __shfl(vnt, j);
                float rv = hrtab[tn * 64 + lane];     // L2-hit, overlaps below
                float acc = 0.f;
                int k = 0;
                int full8 = d & ~7;
                for (; k < full8; k += 8) {
                    float s0 = tl[(buf[eb + k]     >> 20) * 64 + lane];
                    float s1 = tl[(buf[eb + k + 1] >> 20) * 64 + lane];
                    float s2 = tl[(buf[eb + k + 2] >> 20) * 64 + lane];
                    float s3 = tl[(buf[eb + k + 3] >> 20) * 64 + lane];
                    float s4 = tl[(buf[eb + k + 4] >> 20) * 64 + lane];
                    float s5 = tl[(buf[eb + k + 5] >> 20) * 64 + lane];
                    float s6 = tl[(buf[eb + k + 6] >> 20) * 64 + lane];
                    float s7 = tl[(buf[eb + k + 7] >> 20) * 64 + lane];
                    acc += ((s0 + s1) + (s2 + s3)) + ((s4 + s5) + (s6 + s7));
                }
                for (; k < d; ++k)
                    acc += tl[(buf[eb + k] >> 20) * 64 + lane];
                float val = fmaxf(acc * iv + rv, 0.f);
                float vhi = __shfl_down(val, 1);
                if (!(lane & 1))
                    h1p[(size_t)(cb + j) * 32 + (lane >> 1)] = bf16pack2(val, vhi);
            }
        } else {
            // fallback: direct per-node loads (rare; chunk > 512 edges)
            for (int j = 0; j < cn; ++j) {
                int o = __shfl(voff, j), d = __shfl(vdeg, j);
                float iv = __shfl(vinv, j);
                int tn = __shfl(vnt, j);
                float rv = hrtab[tn * 64 + lane];
                float acc = 0.f;
                for (int base = 0; base < d; base += 64) {
                    int rem = d - base; if (rem > 64) rem = 64;
                    int v = (lane < rem) ? csrp[o + base + lane] : 0;
                    for (int k = 0; k < rem; ++k)
                        acc += tl[(__shfl(v, k) >> 20) * 64 + lane];
                }
                float val = fmaxf(acc * iv + rv, 0.f);
                float vhi = __shfl_down(val, 1);
                if (!(lane & 1))
                    h1p[(size_t)(cb + j) * 32 + (lane >> 1)] = bf16pack2(val, vhi);
            }
        }
    }
}

// conv2 dense GEMMs on MFMA bf16 (R10): g1 = h1@W2l, r1 = h1@W2r + b2.
__global__ __launch_bounds__(256) void k_lin2(
    const unsigned* __restrict__ h1p, const float* __restrict__ W2l,
    const float* __restrict__ W2r, const float* __restrict__ b2,
    unsigned* __restrict__ g1p, unsigned* __restrict__ r1p, int n_nodes) {
    __shared__ uint4 sB[2][4][2][64];    // [mat][nblk][kstep][lane]
    __shared__ float sb2[64];
    int tid = threadIdx.x;
    for (int i = tid; i < 1024; i += 256) {
        int mat = i >> 9, nb = (i >> 7) & 3, ks = (i >> 6) & 1, ln = i & 63;
        const float* W = mat ? W2r : W2l;
        int col = nb * 16 + (ln & 15);
        int kbase = ks * 32 + (ln >> 4) * 8;
        unsigned p0 = bf16pack2(W[(kbase + 0) * 64 + col], W[(kbase + 1) * 64 + col]);
        unsigned p1 = bf16pack2(W[(kbase + 2) * 64 + col], W[(kbase + 3) * 64 + col]);
        unsigned p2 = bf16pack2(W[(kbase + 4) * 64 + col], W[(kbase + 5) * 64 + col]);
        unsigned p3 = bf16pack2(W[(kbase + 6) * 64 + col], W[(kbase + 7) * 64 + col]);
        sB[mat][nb][ks][ln] = make_uint4(p0, p1, p2, p3);
    }
    if (tid < 64) sb2[tid] = b2[tid];
    __syncthreads();

    int w = tid >> 6, lane = tid & 63;
    int kg = lane >> 4;
    unsigned short* gh = (unsigned short*)g1p;
    unsigned short* rh = (unsigned short*)r1p;
    int ntile = (n_nodes + 63) >> 6;

    for (int t = blockIdx.x; t < ntile; t += gridDim.x) {
        int n0 = t << 6;
        int row = n0 + w * 16 + (lane & 15);
        int rowc = row < n_nodes ? row : n_nodes - 1;
        uint4 a0u = *(const uint4*)(h1p + (size_t)rowc * 32 + kg * 4);
        uint4 a1u = *(const uint4*)(h1p + (size_t)rowc * 32 + 16 + kg * 4);
        bf16x8 A0 = __builtin_bit_cast(bf16x8, a0u);
        bf16x8 A1 = __builtin_bit_cast(bf16x8, a1u);

        f32x4 accg[4], accr[4];
#pragma unroll
        for (int nb = 0; nb < 4; ++nb) {
            f32x4 z = {0.f, 0.f, 0.f, 0.f};
            bf16x8 Bg0 = __builtin_bit_cast(bf16x8, sB[0][nb][0][lane]);
            bf16x8 Bg1 = __builtin_bit_cast(bf16x8, sB[0][nb][1][lane]);
            bf16x8 Br0 = __builtin_bit_cast(bf16x8, sB[1][nb][0][lane]);
            bf16x8 Br1 = __builtin_bit_cast(bf16x8, sB[1][nb][1][lane]);
            accg[nb] = __builtin_amdgcn_mfma_f32_16x16x32_bf16(A0, Bg0, z, 0, 0, 0);
            accg[nb] = __builtin_amdgcn_mfma_f32_16x16x32_bf16(A1, Bg1, accg[nb], 0, 0, 0);
            accr[nb] = __builtin_amdgcn_mfma_f32_16x16x32_bf16(A0, Br0, z, 0, 0, 0);
            accr[nb] = __builtin_amdgcn_mfma_f32_16x16x32_bf16(A1, Br1, accr[nb], 0, 0, 0);
        }
        // C/D layout (verified, guide §3): col = lane&15, row = (lane>>4)*4 + reg
#pragma unroll
        for (int nb = 0; nb < 4; ++nb) {
            int col = nb * 16 + (lane & 15);
            float bias = sb2[col];
#pragma unroll
            for (int reg = 0; reg < 4; ++reg) {
                int r2 = n0 + w * 16 + kg * 4 + reg;
                if (r2 < n_nodes) {
                    gh[(size_t)r2 * 64 + col] = (unsigned short)bf16rn(accg[nb][reg]);
                    rh[(size_t)r2 * 64 + col] = (unsigned short)bf16rn(accr[nb][reg] + bias);
                }
            }
        }
    }
}

// conv2 aggregation + relu + W_out + pooling. R8 feature-pair scheme (proven
// 42us floor); r1p row load hoisted; NO cross-node prefetch (R14 lesson).
__global__ __launch_bounds__(256) void k_gather2(
    const int* __restrict__ csrp, const int* __restrict__ off,
    const int* __restrict__ deg_i, const float* __restrict__ inv,
    const unsigned* __restrict__ g1p, const unsigned* __restrict__ r1p,
    const int* __restrict__ batch, const float* __restrict__ Wout,
    float* __restrict__ outacc, float* __restrict__ cnt, int n_nodes) {
    int lane = threadIdx.x & 63;
    int li = lane & 31;                       // feature-pair index (uint in row)
    int hi = lane >> 5;                       // 0: even edges, 1: odd edges
    float hm = hi ? 0.f : 1.f;                // mask so halves don't double-count
    int w = blockIdx.x * 4 + (threadIdx.x >> 6);
    int nw = gridDim.x * 4;
    int per = (n_nodes + nw - 1) / nw;
    int n0 = w * per;
    int n1 = n0 + per; if (n1 > n_nodes) n1 = n_nodes;
    float4 wo = *(const float4*)(Wout + li * 4);   // W[2li][0..1], W[2li+1][0..1]
    float p0 = 0.f, p1 = 0.f, pc = 0.f;
    int curg = -1;
    for (int cb = n0; cb < n1; cb += 64) {
        int cn = n1 - cb; if (cn > 64) cn = 64;
        int voff = 0, vdeg = 0, vbat = 0; float vinv = 0.f;
        if (lane < cn) {
            voff = off[cb + lane]; vdeg = deg_i[cb + lane];
            vinv = inv[cb + lane]; vbat = batch[cb + lane];
        }
        for (int j = 0; j < cn; ++j) {
            int o = __shfl(voff, j), d = __shfl(vdeg, j), g = __shfl(vbat, j);
            float iv = __shfl(vinv, j);
            unsigned ur = r1p[(size_t)(cb + j) * 32 + li];   // hoisted (R12)
            float accL = 0.f, accH = 0.f;     // features 2li, 2li+1
            for (int base = 0; base < d; base += 64) {
                int rem = d - base; if (rem > 64) rem = 64;
                int v = (lane < rem) ? csrp[o + base + lane] : 0;
                int k = 0;
                int full8 = rem & ~7;
                for (; k < full8; k += 8) {   // 4 pairs = 8 edges, 4 loads in flight
                    int a0 = __shfl(v, k),     a1 = __shfl(v, k + 1);
                    int a2 = __shfl(v, k + 2), a3 = __shfl(v, k + 3);
                    int a4 = __shfl(v, k + 4), a5 = __shfl(v, k + 5);
                    int a6 = __shfl(v, k + 6), a7 = __shfl(v, k + 7);
                    size_t s0 = (size_t)((hi ? a1 : a0) & 0xFFFFF);
                    size_t s1 = (size_t)((hi ? a3 : a2) & 0xFFFFF);
                    size_t s2 = (size_t)((hi ? a5 : a4) & 0xFFFFF);
                    size_t s3 = (size_t)((hi ? a7 : a6) & 0xFFFFF);
                    unsigned u0 = g1p[s0 * 32 + li];
                    unsigned u1 = g1p[s1 * 32 + li];
                    unsigned u2 = g1p[s2 * 32 + li];
                    unsigned u3 = g1p[s3 * 32 + li];
                    accL += (__uint_as_float(u0 << 16) + __uint_as_float(u1 << 16)) +
                            (__uint_as_float(u2 << 16) + __uint_as_float(u3 << 16));
                    accH += (__uint_as_float(u0 & 0xFFFF0000u) + __uint_as_float(u1 & 0xFFFF0000u)) +
                            (__uint_as_float(u2 & 0xFFFF0000u) + __uint_as_float(u3 & 0xFFFF0000u));
                }
                for (; k + 1 < rem; k += 2) { // single pair
                    int a0 = __shfl(v, k), a1 = __shfl(v, k + 1);
                    size_t s = (size_t)((hi ? a1 : a0) & 0xFFFFF);
                    unsigned u = g1p[s * 32 + li];
                    accL += __uint_as_float(u << 16);
                    accH += __uint_as_float(u & 0xFFFF0000u);
                }
                if (k < rem) {                // odd tail: only hi==0 half counts
                    size_t s = (size_t)(__shfl(v, k) & 0xFFFFF);
                    unsigned u = g1p[s * 32 + li];
                    accL += hm * __uint_as_float(u << 16);
                    accH += hm * __uint_as_float(u & 0xFFFF0000u);
                }
            }
            accL += __shfl_xor(accL, 32);     // merge even/odd halves
            accH += __shfl_xor(accH, 32);
            float v0 = fmaxf(accL * iv + __uint_as_float(ur << 16), 0.f);
            float v1 = fmaxf(accH * iv + __uint_as_float(ur & 0xFFFF0000u), 0.f);
            if (g != curg) {                  // wave-uniform branch
                float q0 = p0, q1 = p1;
#pragma unroll
                for (int m = 1; m < 64; m <<= 1) { q0 += __shfl_xor(q0, m); q1 += __shfl_xor(q1, m); }
                if (lane == 0 && curg >= 0) {
                    atomicAdd(&outacc[curg * 2 + 0], q0);
                    atomicAdd(&outacc[curg * 2 + 1], q1);
                    atomicAdd(&cnt[curg], pc);
                }
                p0 = 0.f; p1 = 0.f; pc = 0.f; curg = g;
            }
            p0 += hm * (v0 * wo.x + v1 * wo.z);
            p1 += hm * (v0 * wo.y + v1 * wo.w);
            pc += 1.0f;
        }
    }
    {
        float q0 = p0, q1 = p1;
#pragma unroll
        for (int m = 1; m < 64; m <<= 1) { q0 += __shfl_xor(q0, m); q1 += __shfl_xor(q1, m); }
        if (lane == 0 && curg >= 0) {
            atomicAdd(&outacc[curg * 2 + 0], q0);
            atomicAdd(&outacc[curg * 2 + 1], q1);
            atomicAdd(&cnt[curg], pc);
        }
    }
}

__global__ void k_out(const float* __restrict__ outacc, const float* __restrict__ cnt,
                      const float* __restrict__ bout, float* __restrict__ out, int n_graphs) {
    int i = blockIdx.x * 256 + threadIdx.x;
    if (i < n_graphs * 2) {
        int g = i >> 1, c = i & 1;
        out[i] = outacc[i] / fmaxf(cnt[g], 1.0f) + bout[c];
    }
}

extern "C" void kernel_launch(void* const* d_in, const int* in_sizes, int n_in,
                              void* d_out, int out_size, void* d_ws, size_t ws_size,
                              hipStream_t stream) {
    const int* x     = (const int*)d_in[0];
    const int* ei    = (const int*)d_in[1];
    const int* batch = (const int*)d_in[2];
    const float* se   = (const float*)d_in[4];
    const float* ce   = (const float*)d_in[5];
    const float* Win  = (const float*)d_in[6];
    const float* bin  = (const float*)d_in[7];
    const float* W1l  = (const float*)d_in[8];
    const float* b1   = (const float*)d_in[9];
    const float* W1r  = (const float*)d_in[10];
    const float* W2l  = (const float*)d_in[11];
    const float* b2   = (const float*)d_in[12];
    const float* W2r  = (const float*)d_in[13];
    const float* Wout = (const float*)d_in[14];
    const float* bout = (const float*)d_in[15];
    float* out = (float*)d_out;

    int n_nodes  = in_sizes[0] / 2;
    int n_edges  = in_sizes[1] / 2;
    int n_graphs = out_size / 2;
    const int* src = ei;
    const int* dst = ei + n_edges;
    int nb = (n_nodes + 255) >> 8;               // buckets (<= 512 for n<131072)

    char* p = (char*)d_ws;
    auto take = [&](size_t bytes) { char* r = p; p += (bytes + 255) & ~(size_t)255; return r; };
    unsigned* h1p    = (unsigned*)take((size_t)n_nodes * 32 * 4);
    unsigned* g1p    = (unsigned*)take((size_t)n_nodes * 32 * 4);
    unsigned* r1p    = (unsigned*)take((size_t)n_nodes * 32 * 4);
    int*      csrp   = (int*)take((size_t)n_edges * 4);
    int*      bedge  = (int*)take((size_t)n_edges * 4);
    int*      ntype  = (int*)take((size_t)n_nodes * 4);
    int*      deg_i  = (int*)take((size_t)n_nodes * 4);
    int*      off    = (int*)take((size_t)n_nodes * 4);
    float*    inv    = (float*)take((size_t)n_nodes * 4);
    int*      histT  = (int*)take((size_t)512 * NBLK * 4);
    int*      blkOff = (int*)take((size_t)512 * NBLK * 4);
    int*      btot   = (int*)take(512 * 4);
    float*    cnt    = (float*)take((size_t)n_graphs * 4);
    float*    outacc = (float*)take((size_t)n_graphs * 8);
    float*    hltab  = (float*)take(4096 * 4);
    float*    hrtab  = (float*)take(4096 * 4);

    int nbN = (n_nodes + 255) / 256;

    k_front<<<NBLK + 64 + nbN, 256, 0, stream>>>(dst, histT, n_edges, nb,
                                                 se, ce, Win, bin, W1l, W1r, b1,
                                                 hltab, hrtab, x, ntype, cnt, outacc,
                                                 n_nodes, n_graphs);
    k_bscan<<<nb, 256, 0, stream>>>(histT, blkOff, btot);
    k_scatter<<<NBLK, 256, 0, stream>>>(src, dst, ntype, btot, blkOff, bedge, n_edges, nb);
    k_bsort<<<nb, 256, 0, stream>>>(bedge, btot, csrp, deg_i, off, inv, n_nodes, nb);
    k_gather1<<<2048, 256, 0, stream>>>(csrp, off, deg_i, inv, ntype, hltab, hrtab, h1p, n_nodes);
    k_lin2<<<1024, 256, 0, stream>>>(h1p, W2l, W2r, b2, g1p, r1p, n_nodes);
    k_gather2<<<2048, 256, 0, stream>>>(csrp, off, deg_i, inv, g1p, r1p, batch, Wout,
                                        outacc, cnt, n_nodes);
    k_out<<<(n_graphs * 2 + 255) / 256, 256, 0, stream>>>(outacc, cnt, bout, out, n_graphs);
}